// Round 1
// baseline (4042.719 us; speedup 1.0000x reference)
//
#include <hip/hip_runtime.h>
#include <hip/hip_bf16.h>
#include <math.h>

// Problem constants
#define T_     1024
#define DIM_   2048
#define H_     16
#define QLR_   1024
#define KVLR_  512
#define NOPE_  128
#define ROPE_  64
#define VD_    128
#define QKD_   192   // NOPE+ROPE
#define IH_    16
#define ID_    128
#define TOPK_  256
#define CKV_   576   // KVLR + ROPE

#define SCALE_W    0.022097086912079608f   // IH^-0.5 * ID^-0.5
#define SCALE_LOG  0.07216878364870323f    // QKD^-0.5

// ---------------------------------------------------------------------------
// Generic tiled SGEMM, C[m,n] = alpha * rowscale[m] * sum_k (A[m,k]*colw[k]) * B[n,k]
// A: M x K row-major, B: N x K row-major (i.e. C = A @ B^T), C: M x N.
// K must be a multiple of 16. M,N guarded.
// ---------------------------------------------------------------------------
__global__ __launch_bounds__(256) void gemm_nt_k(
    const float* __restrict__ A, const float* __restrict__ B, float* __restrict__ C,
    int M, int N, int K, float alpha,
    const float* __restrict__ colw, const float* __restrict__ rowscale)
{
    __shared__ float As[16][65];
    __shared__ float Bs[16][65];
    const int tid = threadIdx.x;
    const int tx = tid & 15, ty = tid >> 4;
    const int bm = blockIdx.y * 64, bn = blockIdx.x * 64;
    float acc[4][4] = {};

    for (int k0 = 0; k0 < K; k0 += 16) {
        #pragma unroll
        for (int r = 0; r < 4; ++r) {
            int m = ty + r * 16;
            int gm = bm + m, gk = k0 + tx;
            float v = (gm < M) ? A[(long)gm * K + gk] : 0.f;
            if (colw) v *= colw[gk];
            As[tx][m] = v;
        }
        #pragma unroll
        for (int r = 0; r < 4; ++r) {
            int n = ty + r * 16;
            int gn = bn + n, gk = k0 + tx;
            Bs[tx][n] = (gn < N) ? B[(long)gn * K + gk] : 0.f;
        }
        __syncthreads();
        #pragma unroll
        for (int kk = 0; kk < 16; ++kk) {
            float a[4], b[4];
            #pragma unroll
            for (int i = 0; i < 4; ++i) a[i] = As[kk][ty * 4 + i];
            #pragma unroll
            for (int j = 0; j < 4; ++j) b[j] = Bs[kk][tx * 4 + j];
            #pragma unroll
            for (int i = 0; i < 4; ++i)
                #pragma unroll
                for (int j = 0; j < 4; ++j) acc[i][j] += a[i] * b[j];
        }
        __syncthreads();
    }

    #pragma unroll
    for (int i = 0; i < 4; ++i) {
        int gm = bm + ty * 4 + i;
        if (gm >= M) continue;
        float rs = alpha * (rowscale ? rowscale[gm] : 1.f);
        #pragma unroll
        for (int j = 0; j < 4; ++j) {
            int gn = bn + tx * 4 + j;
            if (gn < N) C[(long)gm * N + gn] = acc[i][j] * rs;
        }
    }
}

// ---------------------------------------------------------------------------
// Batched NN GEMM: Cb[m,n] = sum_k Ab[m,k] * Bb[k,n], batch = blockIdx.z.
// All dims must be multiples of tile (M%64==0, N%64==0, K%16==0).
// ---------------------------------------------------------------------------
__global__ __launch_bounds__(256) void gemm_nn_b_k(
    const float* __restrict__ A, const float* __restrict__ B, float* __restrict__ C,
    long sAb, long sBb, long sCb, int lda, int ldb, int ldc, int M, int N, int K)
{
    const float* Ab = A + (long)blockIdx.z * sAb;
    const float* Bb = B + (long)blockIdx.z * sBb;
    float* Cb = C + (long)blockIdx.z * sCb;
    __shared__ float As[16][65];
    __shared__ float Bs[16][65];
    const int tid = threadIdx.x;
    const int tx = tid & 15, ty = tid >> 4;
    const int bm = blockIdx.y * 64, bn = blockIdx.x * 64;
    float acc[4][4] = {};

    for (int k0 = 0; k0 < K; k0 += 16) {
        #pragma unroll
        for (int r = 0; r < 4; ++r) {
            int m = ty + r * 16;
            As[tx][m] = Ab[(long)(bm + m) * lda + k0 + tx];
        }
        {
            int n = tid & 63, kk0 = tid >> 6;
            #pragma unroll
            for (int r = 0; r < 4; ++r) {
                int kk = kk0 + r * 4;
                Bs[kk][n] = Bb[(long)(k0 + kk) * ldb + bn + n];
            }
        }
        __syncthreads();
        #pragma unroll
        for (int kk = 0; kk < 16; ++kk) {
            float a[4], b[4];
            #pragma unroll
            for (int i = 0; i < 4; ++i) a[i] = As[kk][ty * 4 + i];
            #pragma unroll
            for (int j = 0; j < 4; ++j) b[j] = Bs[kk][tx * 4 + j];
            #pragma unroll
            for (int i = 0; i < 4; ++i)
                #pragma unroll
                for (int j = 0; j < 4; ++j) acc[i][j] += a[i] * b[j];
        }
        __syncthreads();
    }
    #pragma unroll
    for (int i = 0; i < 4; ++i)
        #pragma unroll
        for (int j = 0; j < 4; ++j)
            Cb[(long)(bm + ty * 4 + i) * ldc + bn + tx * 4 + j] = acc[i][j];
}

// ---------------------------------------------------------------------------
// Per-row 1/rms of qr (shared by both rmsnorm(qr, *) uses; EPS=1e-6)
// ---------------------------------------------------------------------------
__global__ __launch_bounds__(256) void rstd_k(const float* __restrict__ qr, float* __restrict__ rstd)
{
    int t = blockIdx.x, tid = threadIdx.x;
    float s = 0.f;
    for (int c = tid; c < QLR_; c += 256) { float v = qr[(long)t * QLR_ + c]; s += v * v; }
    __shared__ float red[256];
    red[tid] = s; __syncthreads();
    for (int off = 128; off; off >>= 1) { if (tid < off) red[tid] += red[tid + off]; __syncthreads(); }
    if (tid == 0) rstd[t] = rsqrtf(red[0] / (float)QLR_ + 1e-6f);
}

// ---------------------------------------------------------------------------
// rope (first 64 of 128) + rotate_activation (swap halves, WHT-64 each)
// s: 128 shared floats (input, clobbered); w2: 128 shared scratch (output).
// Must be called by all 128 threads.
// ---------------------------------------------------------------------------
__device__ __forceinline__ void rope_rotate_128(float* s, float* w2, int tid, int t,
    const float* __restrict__ cosb, const float* __restrict__ sinb)
{
    float n1 = 0.f, n2 = 0.f;
    if (tid < 32) {
        float x1 = s[tid], x2 = s[tid + 32];
        float c = cosb[t * 32 + tid], sn = sinb[t * 32 + tid];
        n1 = x1 * c - x2 * sn;
        n2 = x1 * sn + x2 * c;
    }
    __syncthreads();
    if (tid < 32) { s[tid] = n1; s[tid + 32] = n2; }
    __syncthreads();
    // rotate: out first half = WHT(second half), out second half = WHT(first half)
    const int g = tid >> 6, p = tid & 63;
    w2[tid] = s[((1 - g) << 6) + p];
    __syncthreads();
    #pragma unroll
    for (int h = 1; h < 64; h <<= 1) {
        float a = w2[tid], b = w2[(g << 6) + (p ^ h)];
        __syncthreads();
        w2[tid] = (p & h) ? (b - a) : (a + b);
        __syncthreads();
    }
}

__global__ __launch_bounds__(128) void transform_iq_k(float* __restrict__ iq,
    const float* __restrict__ cosb, const float* __restrict__ sinb)
{
    int row = blockIdx.x;          // t*IH + h
    int t = row / IH_;
    int tid = threadIdx.x;
    __shared__ float s[128], w2[128];
    s[tid] = iq[(long)row * 128 + tid];
    __syncthreads();
    rope_rotate_128(s, w2, tid, t, cosb, sinb);
    iq[(long)row * 128 + tid] = w2[tid];
}

__global__ __launch_bounds__(128) void transform_ik_k(float* __restrict__ ik,
    const float* __restrict__ knw, const float* __restrict__ knb,
    const float* __restrict__ cosb, const float* __restrict__ sinb)
{
    int row = blockIdx.x;
    int t = row / IH_;
    int tid = threadIdx.x;
    __shared__ float s[128], w2[128], red[128];
    float v = ik[(long)row * 128 + tid];
    red[tid] = v; __syncthreads();
    for (int off = 64; off; off >>= 1) { if (tid < off) red[tid] += red[tid + off]; __syncthreads(); }
    float m = red[0] / 128.f; __syncthreads();
    float d = v - m;
    red[tid] = d * d; __syncthreads();
    for (int off = 64; off; off >>= 1) { if (tid < off) red[tid] += red[tid + off]; __syncthreads(); }
    float var = red[0] / 128.f;
    s[tid] = d * rsqrtf(var + 1e-5f) * knw[tid] + knb[tid];
    __syncthreads();
    rope_rotate_128(s, w2, tid, t, cosb, sinb);
    ik[(long)row * 128 + tid] = w2[tid];
}

// kv_key[t, :512] = rmsnorm(kva[t,:512], kv_norm_w); kv_key[t, 512:576] = rope(kva[t,512:576])
__global__ __launch_bounds__(256) void transform_kv_k(const float* __restrict__ kva,
    float* __restrict__ kvkey, const float* __restrict__ kvnw,
    const float* __restrict__ cosb, const float* __restrict__ sinb)
{
    int t = blockIdx.x, tid = threadIdx.x;
    const float* a = kva + (long)t * CKV_;
    float* o = kvkey + (long)t * CKV_;
    float v0 = a[tid], v1 = a[tid + 256];
    __shared__ float red[256];
    __shared__ float rsh;
    red[tid] = v0 * v0 + v1 * v1; __syncthreads();
    for (int off = 128; off; off >>= 1) { if (tid < off) red[tid] += red[tid + off]; __syncthreads(); }
    if (tid == 0) rsh = rsqrtf(red[0] / (float)KVLR_ + 1e-6f);
    __syncthreads();
    float rs = rsh;
    o[tid]       = v0 * rs * kvnw[tid];
    o[tid + 256] = v1 * rs * kvnw[tid + 256];
    if (tid < 32) {
        float x1 = a[512 + tid], x2 = a[544 + tid];
        float c = cosb[t * 32 + tid], sn = sinb[t * 32 + tid];
        o[512 + tid] = x1 * c - x2 * sn;
        o[544 + tid] = x1 * sn + x2 * c;
    }
}

// q_key[t,h,512:576] = rope(q[t,h,128:192]); 2 rows per 64-thread block
__global__ __launch_bounds__(64) void qpe_k(const float* __restrict__ q, float* __restrict__ qkey,
    const float* __restrict__ cosb, const float* __restrict__ sinb)
{
    int row = blockIdx.x * 2 + (threadIdx.x >> 5);   // t*H + h
    int i = threadIdx.x & 31;
    int t = row / H_;
    const float* qp = q + (long)row * QKD_ + NOPE_;
    float x1 = qp[i], x2 = qp[i + 32];
    float c = cosb[t * 32 + i], sn = sinb[t * 32 + i];
    float* o = qkey + (long)row * CKV_ + 512;
    o[i]      = x1 * c - x2 * sn;
    o[i + 32] = x1 * sn + x2 * c;
}

// ---------------------------------------------------------------------------
// Indexer score: score[t,s] = sum_h relu(iq[t,h,:]·ik[s,h,:]) * wtok[t,h]
// Only lower-triangle 64x64 blocks computed; upper left as garbage (topk masks).
// ---------------------------------------------------------------------------
__global__ __launch_bounds__(256) void score_k(const float* __restrict__ iq,
    const float* __restrict__ ik, const float* __restrict__ wtok, float* __restrict__ score)
{
    int bt = blockIdx.y, bs = blockIdx.x;
    if (bs > bt) return;
    __shared__ float As[16][65];
    __shared__ float Bs[16][65];
    const int tid = threadIdx.x;
    const int tx = tid & 15, ty = tid >> 4;
    const int t0 = bt * 64, s0 = bs * 64;
    float accf[4][4] = {};

    for (int h = 0; h < IH_; ++h) {
        float acch[4][4] = {};
        for (int k0 = 0; k0 < ID_; k0 += 16) {
            #pragma unroll
            for (int r = 0; r < 4; ++r) {
                int m = ty + r * 16;
                As[tx][m] = iq[((long)(t0 + m) * IH_ + h) * ID_ + k0 + tx];
                Bs[tx][m] = ik[((long)(s0 + m) * IH_ + h) * ID_ + k0 + tx];
            }
            __syncthreads();
            #pragma unroll
            for (int kk = 0; kk < 16; ++kk) {
                float a[4], b[4];
                #pragma unroll
                for (int i = 0; i < 4; ++i) a[i] = As[kk][ty * 4 + i];
                #pragma unroll
                for (int j = 0; j < 4; ++j) b[j] = Bs[kk][tx * 4 + j];
                #pragma unroll
                for (int i = 0; i < 4; ++i)
                    #pragma unroll
                    for (int j = 0; j < 4; ++j) acch[i][j] += a[i] * b[j];
            }
            __syncthreads();
        }
        #pragma unroll
        for (int i = 0; i < 4; ++i) {
            float wv = wtok[(long)(t0 + ty * 4 + i) * IH_ + h];
            #pragma unroll
            for (int j = 0; j < 4; ++j) accf[i][j] += fmaxf(acch[i][j], 0.f) * wv;
        }
    }
    #pragma unroll
    for (int i = 0; i < 4; ++i) {
        int t = t0 + ty * 4 + i;
        #pragma unroll
        for (int j = 0; j < 4; ++j) score[(long)t * T_ + s0 + tx * 4 + j] = accf[i][j];
    }
}

// ---------------------------------------------------------------------------
// Top-256 per row via bitonic sort of 1024 (value,index) pairs, descending,
// ties -> lower index first (matches jax.lax.top_k). Causal mask applied here.
// ---------------------------------------------------------------------------
__global__ __launch_bounds__(512) void topk_k(const float* __restrict__ score, int* __restrict__ topk)
{
    int t = blockIdx.x, tid = threadIdx.x;
    __shared__ float v[1024];
    __shared__ int ix[1024];
    for (int i = tid; i < 1024; i += 512) {
        v[i] = (i <= t) ? score[(long)t * T_ + i] : -INFINITY;
        ix[i] = i;
    }
    __syncthreads();
    for (int k = 2; k <= 1024; k <<= 1) {
        for (int j = k >> 1; j > 0; j >>= 1) {
            for (int i = tid; i < 1024; i += 512) {
                int l = i ^ j;
                if (l > i) {
                    bool up = ((i & k) == 0);   // region sorted descending when up
                    float vi = v[i], vl = v[l];
                    int xi = ix[i], xl = ix[l];
                    bool iBetter = (vi > vl) || (vi == vl && xi < xl);
                    bool doSwap = up ? !iBetter : iBetter;
                    if (doSwap) { v[i] = vl; v[l] = vi; ix[i] = xl; ix[l] = xi; }
                }
            }
            __syncthreads();
        }
    }
    if (tid < 256) topk[(long)t * TOPK_ + tid] = ix[tid];
}

// ---------------------------------------------------------------------------
// Attention per (t,h): logits over 256 gathered keys, softmax, out_latent(512),
// then out_v[t,h,:] = out_latent @ w_v[h]^T (w_v from wkv_b rows h*256+128..h*256+255)
// ---------------------------------------------------------------------------
__global__ __launch_bounds__(256) void attn_k(
    const float* __restrict__ qkey, const float* __restrict__ kvkey,
    const int* __restrict__ topk, const float* __restrict__ wkv_b,
    float* __restrict__ outv)
{
    int t = blockIdx.x, h = blockIdx.y, tid = threadIdx.x;
    __shared__ float qk[CKV_];
    __shared__ float attn[256];
    __shared__ int kidx[256];
    __shared__ float lat[512];
    __shared__ float red[256];

    const float* qrow = qkey + ((long)t * H_ + h) * CKV_;
    for (int c = tid; c < CKV_; c += 256) qk[c] = qrow[c];
    int ki = topk[(long)t * TOPK_ + tid];
    kidx[tid] = ki;
    bool valid = (ki <= t);
    __syncthreads();

    float logit = -INFINITY;
    if (valid) {
        const float* krow = kvkey + (long)ki * CKV_;
        float s = 0.f;
        for (int c = 0; c < CKV_; ++c) s += qk[c] * krow[c];
        logit = s * SCALE_LOG;
    }
    red[tid] = logit; __syncthreads();
    for (int off = 128; off; off >>= 1) { if (tid < off) red[tid] = fmaxf(red[tid], red[tid + off]); __syncthreads(); }
    float mx = red[0]; __syncthreads();
    float e = valid ? expf(logit - mx) : 0.f;
    red[tid] = e; __syncthreads();
    for (int off = 128; off; off >>= 1) { if (tid < off) red[tid] += red[tid + off]; __syncthreads(); }
    float sum = red[0]; __syncthreads();
    attn[tid] = e / sum;
    __syncthreads();

    for (int c = tid; c < 512; c += 256) {
        float acc = 0.f;
        for (int k = 0; k < 256; ++k) acc += attn[k] * kvkey[(long)kidx[k] * CKV_ + c];
        lat[c] = acc;
    }
    __syncthreads();

    if (tid < 128) {
        const float* wv = wkv_b + (long)(h * 256 + 128 + tid) * KVLR_;
        float acc = 0.f;
        for (int c = 0; c < 512; ++c) acc += lat[c] * wv[c];
        outv[(long)t * (H_ * VD_) + h * VD_ + tid] = acc;
    }
}

// ---------------------------------------------------------------------------
extern "C" void kernel_launch(void* const* d_in, const int* in_sizes, int n_in,
                              void* d_out, int out_size, void* d_ws, size_t ws_size,
                              hipStream_t stream)
{
    const float* x          = (const float*)d_in[0];
    const float* cosb       = (const float*)d_in[1];
    const float* sinb       = (const float*)d_in[2];
    const float* wq_a       = (const float*)d_in[3];
    const float* q_norm_w   = (const float*)d_in[4];
    const float* wq_b       = (const float*)d_in[5];
    const float* wkv_a      = (const float*)d_in[6];
    const float* kv_norm_w  = (const float*)d_in[7];
    const float* wkv_b      = (const float*)d_in[8];
    const float* wo         = (const float*)d_in[9];
    const float* iq_norm_w  = (const float*)d_in[10];
    const float* iwq_b      = (const float*)d_in[11];
    const float* iwk        = (const float*)d_in[12];
    const float* k_norm_w   = (const float*)d_in[13];
    const float* k_norm_b   = (const float*)d_in[14];
    const float* wproj      = (const float*)d_in[15];
    float* out = (float*)d_out;

    // workspace layout (floats)
    float* ws    = (float*)d_ws;
    float* qr    = ws;                                  // T*QLR      = 1048576
    float* rstd  = qr    + (long)T_ * QLR_;             // T          = 1024
    float* wtok  = rstd  + T_;                          // T*IH       = 16384
    float* iq    = wtok  + (long)T_ * IH_;              // T*IH*ID    = 2097152
    float* ik    = iq    + (long)T_ * IH_ * ID_;        // T*IH*ID    = 2097152
    float* kva   = ik    + (long)T_ * IH_ * ID_;        // T*576      = 589824
    float* kvkey = kva   + (long)T_ * CKV_;             // T*576      = 589824
    float* score = kvkey + (long)T_ * CKV_;             // T*T        = 1048576
    int*   topk  = (int*)(score + (long)T_ * T_);       // T*TOPK     = 262144 ints
    float* q     = (float*)(topk + (long)T_ * TOPK_);   // T*H*QKD    = 3145728
    float* qkey  = q     + (long)T_ * H_ * QKD_;        // T*H*576    = 9437184
    float* outv  = qkey  + (long)T_ * H_ * CKV_;        // T*H*VD     = 2097152

    // 1. qr = x @ wq_a.T                         (1024 x 1024 x 2048)
    gemm_nt_k<<<dim3(QLR_ / 64, T_ / 64), 256, 0, stream>>>(x, wq_a, qr, T_, QLR_, DIM_, 1.f, nullptr, nullptr);
    // 2. per-row 1/rms of qr
    rstd_k<<<T_, 256, 0, stream>>>(qr, rstd);
    // 3. wtok = x @ wproj.T * IH^-.5 * ID^-.5    (1024 x 16 x 2048)
    gemm_nt_k<<<dim3(1, T_ / 64), 256, 0, stream>>>(x, wproj, wtok, T_, IH_, DIM_, SCALE_W, nullptr, nullptr);
    // 4. ikraw = x @ iwk.T                       (1024 x 2048 x 2048)
    gemm_nt_k<<<dim3(IH_ * ID_ / 64, T_ / 64), 256, 0, stream>>>(x, iwk, ik, T_, IH_ * ID_, DIM_, 1.f, nullptr, nullptr);
    // 5. kva = x @ wkv_a.T                       (1024 x 576 x 2048)
    gemm_nt_k<<<dim3(CKV_ / 64, T_ / 64), 256, 0, stream>>>(x, wkv_a, kva, T_, CKV_, DIM_, 1.f, nullptr, nullptr);
    // 6. iq = rmsnorm(qr, iq_norm_w) @ iwq_b.T   (1024 x 2048 x 1024)
    gemm_nt_k<<<dim3(IH_ * ID_ / 64, T_ / 64), 256, 0, stream>>>(qr, iwq_b, iq, T_, IH_ * ID_, QLR_, 1.f, iq_norm_w, rstd);
    // 7. q = rmsnorm(qr, q_norm_w) @ wq_b.T      (1024 x 3072 x 1024)
    gemm_nt_k<<<dim3(H_ * QKD_ / 64, T_ / 64), 256, 0, stream>>>(qr, wq_b, q, T_, H_ * QKD_, QLR_, 1.f, q_norm_w, rstd);
    // 8-10. per-row transforms
    transform_iq_k<<<T_ * IH_, 128, 0, stream>>>(iq, cosb, sinb);
    transform_ik_k<<<T_ * IH_, 128, 0, stream>>>(ik, k_norm_w, k_norm_b, cosb, sinb);
    transform_kv_k<<<T_, 256, 0, stream>>>(kva, kvkey, kv_norm_w, cosb, sinb);
    // 11. q_key rope part
    qpe_k<<<T_ * H_ / 2, 64, 0, stream>>>(q, qkey, cosb, sinb);
    // 12. q_key nope part: per-head q_nope @ w_k[h]   (batched 1024 x 512 x 128)
    gemm_nn_b_k<<<dim3(KVLR_ / 64, T_ / 64, H_), 256, 0, stream>>>(
        q, wkv_b, qkey,
        (long)QKD_, (long)(NOPE_ + VD_) * KVLR_, (long)CKV_,
        H_ * QKD_, KVLR_, H_ * CKV_, T_, KVLR_, NOPE_);
    // 13. indexer scores (lower triangle)
    score_k<<<dim3(T_ / 64, T_ / 64), 256, 0, stream>>>(iq, ik, wtok, score);
    // 14. top-256 per row
    topk_k<<<T_, 512, 0, stream>>>(score, topk);
    // 15. attention -> outv
    attn_k<<<dim3(T_, H_), 256, 0, stream>>>(qkey, kvkey, topk, wkv_b, outv);
    // 16. out = outv @ wo.T                      (1024 x 2048 x 2048)
    gemm_nt_k<<<dim3(DIM_ / 64, T_ / 64), 256, 0, stream>>>(outv, wo, out, T_, DIM_, H_ * VD_, 1.f, nullptr, nullptr);

    (void)in_sizes; (void)n_in; (void)out_size; (void)ws_size;
}

// Round 2
// 1570.907 us; speedup vs baseline: 2.5735x; 2.5735x over previous
//
#include <hip/hip_runtime.h>
#include <hip/hip_bf16.h>
#include <math.h>

// Problem constants
#define T_     1024
#define DIM_   2048
#define H_     16
#define QLR_   1024
#define KVLR_  512
#define NOPE_  128
#define ROPE_  64
#define VD_    128
#define QKD_   192   // NOPE+ROPE
#define IH_    16
#define ID_    128
#define TOPK_  256
#define CKV_   576   // KVLR + ROPE

#define SCALE_W    0.022097086912079608f   // IH^-0.5 * ID^-0.5
#define SCALE_LOG  0.07216878364870323f    // QKD^-0.5

// ---------------------------------------------------------------------------
// Fast NT GEMM: all of M,N %64==0, K%32==0. C = alpha*rowscale[m]*(A.*colw)@B^T
// Optionally batched via blockIdx.z with strides sA/sB/sC.
// BK=32, float4 staging, b128 LDS reads, 4x4 micro-tile.
// ---------------------------------------------------------------------------
__global__ __launch_bounds__(256) void gemm_nt64_k(
    const float* __restrict__ A, const float* __restrict__ B, float* __restrict__ C,
    long sA, long sB, long sC, int lda, int ldb, int ldc, int K,
    float alpha, const float* __restrict__ colw, const float* __restrict__ rowscale)
{
    const float4* A4 = (const float4*)(A + (long)blockIdx.z * sA);
    const float4* B4 = (const float4*)(B + (long)blockIdx.z * sB);
    float* Cb = C + (long)blockIdx.z * sC;
    __shared__ float As[32][68];
    __shared__ float Bs[32][68];
    const int tid = threadIdx.x;
    const int tx = tid & 15, ty = tid >> 4;
    const int bm = blockIdx.y * 64, bn = blockIdx.x * 64;
    const int um = tid >> 3, uu = tid & 7;
    const int lda4 = lda >> 2, ldb4 = ldb >> 2;
    float acc[4][4] = {};

    for (int k0 = 0; k0 < K; k0 += 32) {
        float4 cw = make_float4(1.f, 1.f, 1.f, 1.f);
        if (colw) cw = ((const float4*)colw)[(k0 >> 2) + uu];
        __syncthreads();
        #pragma unroll
        for (int rep = 0; rep < 2; ++rep) {
            int m = um + 32 * rep;
            float4 a = A4[(long)(bm + m) * lda4 + (k0 >> 2) + uu];
            As[4*uu+0][m] = a.x * cw.x; As[4*uu+1][m] = a.y * cw.y;
            As[4*uu+2][m] = a.z * cw.z; As[4*uu+3][m] = a.w * cw.w;
            float4 b = B4[(long)(bn + m) * ldb4 + (k0 >> 2) + uu];
            Bs[4*uu+0][m] = b.x; Bs[4*uu+1][m] = b.y;
            Bs[4*uu+2][m] = b.z; Bs[4*uu+3][m] = b.w;
        }
        __syncthreads();
        #pragma unroll
        for (int kk = 0; kk < 32; ++kk) {
            const float4 a4 = *(const float4*)&As[kk][4 * ty];
            const float4 b4 = *(const float4*)&Bs[kk][4 * tx];
            const float af[4] = {a4.x, a4.y, a4.z, a4.w};
            const float bf[4] = {b4.x, b4.y, b4.z, b4.w};
            #pragma unroll
            for (int i = 0; i < 4; ++i)
                #pragma unroll
                for (int j = 0; j < 4; ++j) acc[i][j] += af[i] * bf[j];
        }
    }
    #pragma unroll
    for (int i = 0; i < 4; ++i) {
        int gm = bm + 4 * ty + i;
        float rs = alpha * (rowscale ? rowscale[gm] : 1.f);
        float4 o = make_float4(acc[i][0]*rs, acc[i][1]*rs, acc[i][2]*rs, acc[i][3]*rs);
        *(float4*)&Cb[(long)gm * ldc + bn + 4 * tx] = o;
    }
}

// ---------------------------------------------------------------------------
// Guarded slow NT GEMM (kept only for wtok, N=16)
// ---------------------------------------------------------------------------
__global__ __launch_bounds__(256) void gemm_nt_k(
    const float* __restrict__ A, const float* __restrict__ B, float* __restrict__ C,
    int M, int N, int K, float alpha,
    const float* __restrict__ colw, const float* __restrict__ rowscale)
{
    __shared__ float As[16][65];
    __shared__ float Bs[16][65];
    const int tid = threadIdx.x;
    const int tx = tid & 15, ty = tid >> 4;
    const int bm = blockIdx.y * 64, bn = blockIdx.x * 64;
    float acc[4][4] = {};

    for (int k0 = 0; k0 < K; k0 += 16) {
        #pragma unroll
        for (int r = 0; r < 4; ++r) {
            int m = ty + r * 16;
            int gm = bm + m, gk = k0 + tx;
            float v = (gm < M) ? A[(long)gm * K + gk] : 0.f;
            if (colw) v *= colw[gk];
            As[tx][m] = v;
        }
        #pragma unroll
        for (int r = 0; r < 4; ++r) {
            int n = ty + r * 16;
            int gn = bn + n, gk = k0 + tx;
            Bs[tx][n] = (gn < N) ? B[(long)gn * K + gk] : 0.f;
        }
        __syncthreads();
        #pragma unroll
        for (int kk = 0; kk < 16; ++kk) {
            float a[4], b[4];
            #pragma unroll
            for (int i = 0; i < 4; ++i) a[i] = As[kk][ty * 4 + i];
            #pragma unroll
            for (int j = 0; j < 4; ++j) b[j] = Bs[kk][tx * 4 + j];
            #pragma unroll
            for (int i = 0; i < 4; ++i)
                #pragma unroll
                for (int j = 0; j < 4; ++j) acc[i][j] += a[i] * b[j];
        }
        __syncthreads();
    }
    #pragma unroll
    for (int i = 0; i < 4; ++i) {
        int gm = bm + ty * 4 + i;
        if (gm >= M) continue;
        float rs = alpha * (rowscale ? rowscale[gm] : 1.f);
        #pragma unroll
        for (int j = 0; j < 4; ++j) {
            int gn = bn + tx * 4 + j;
            if (gn < N) C[(long)gm * N + gn] = acc[i][j] * rs;
        }
    }
}

// ---------------------------------------------------------------------------
// Batched NN GEMM (q_nope_proj): Cb[m,n] = sum_k Ab[m,k]*Bb[k,n]
// ---------------------------------------------------------------------------
__global__ __launch_bounds__(256) void gemm_nn_b_k(
    const float* __restrict__ A, const float* __restrict__ B, float* __restrict__ C,
    long sAb, long sBb, long sCb, int lda, int ldb, int ldc, int M, int N, int K)
{
    const float* Ab = A + (long)blockIdx.z * sAb;
    const float* Bb = B + (long)blockIdx.z * sBb;
    float* Cb = C + (long)blockIdx.z * sCb;
    __shared__ float As[16][65];
    __shared__ float Bs[16][65];
    const int tid = threadIdx.x;
    const int tx = tid & 15, ty = tid >> 4;
    const int bm = blockIdx.y * 64, bn = blockIdx.x * 64;
    float acc[4][4] = {};

    for (int k0 = 0; k0 < K; k0 += 16) {
        #pragma unroll
        for (int r = 0; r < 4; ++r) {
            int m = ty + r * 16;
            As[tx][m] = Ab[(long)(bm + m) * lda + k0 + tx];
        }
        {
            int n = tid & 63, kk0 = tid >> 6;
            #pragma unroll
            for (int r = 0; r < 4; ++r) {
                int kk = kk0 + r * 4;
                Bs[kk][n] = Bb[(long)(k0 + kk) * ldb + bn + n];
            }
        }
        __syncthreads();
        #pragma unroll
        for (int kk = 0; kk < 16; ++kk) {
            float a[4], b[4];
            #pragma unroll
            for (int i = 0; i < 4; ++i) a[i] = As[kk][ty * 4 + i];
            #pragma unroll
            for (int j = 0; j < 4; ++j) b[j] = Bs[kk][tx * 4 + j];
            #pragma unroll
            for (int i = 0; i < 4; ++i)
                #pragma unroll
                for (int j = 0; j < 4; ++j) acc[i][j] += a[i] * b[j];
        }
        __syncthreads();
    }
    #pragma unroll
    for (int i = 0; i < 4; ++i)
        #pragma unroll
        for (int j = 0; j < 4; ++j)
            Cb[(long)(bm + ty * 4 + i) * ldc + bn + tx * 4 + j] = acc[i][j];
}

// ---------------------------------------------------------------------------
__global__ __launch_bounds__(256) void rstd_k(const float* __restrict__ qr, float* __restrict__ rstd)
{
    int t = blockIdx.x, tid = threadIdx.x;
    float s = 0.f;
    for (int c = tid; c < QLR_; c += 256) { float v = qr[(long)t * QLR_ + c]; s += v * v; }
    __shared__ float red[256];
    red[tid] = s; __syncthreads();
    for (int off = 128; off; off >>= 1) { if (tid < off) red[tid] += red[tid + off]; __syncthreads(); }
    if (tid == 0) rstd[t] = rsqrtf(red[0] / (float)QLR_ + 1e-6f);
}

// ---------------------------------------------------------------------------
__device__ __forceinline__ void rope_rotate_128(float* s, float* w2, int tid, int t,
    const float* __restrict__ cosb, const float* __restrict__ sinb)
{
    float n1 = 0.f, n2 = 0.f;
    if (tid < 32) {
        float x1 = s[tid], x2 = s[tid + 32];
        float c = cosb[t * 32 + tid], sn = sinb[t * 32 + tid];
        n1 = x1 * c - x2 * sn;
        n2 = x1 * sn + x2 * c;
    }
    __syncthreads();
    if (tid < 32) { s[tid] = n1; s[tid + 32] = n2; }
    __syncthreads();
    const int g = tid >> 6, p = tid & 63;
    w2[tid] = s[((1 - g) << 6) + p];
    __syncthreads();
    #pragma unroll
    for (int h = 1; h < 64; h <<= 1) {
        float a = w2[tid], b = w2[(g << 6) + (p ^ h)];
        __syncthreads();
        w2[tid] = (p & h) ? (b - a) : (a + b);
        __syncthreads();
    }
}

__global__ __launch_bounds__(128) void transform_iq_k(float* __restrict__ iq,
    const float* __restrict__ cosb, const float* __restrict__ sinb)
{
    int row = blockIdx.x;
    int t = row / IH_;
    int tid = threadIdx.x;
    __shared__ float s[128], w2[128];
    s[tid] = iq[(long)row * 128 + tid];
    __syncthreads();
    rope_rotate_128(s, w2, tid, t, cosb, sinb);
    iq[(long)row * 128 + tid] = w2[tid];
}

__global__ __launch_bounds__(128) void transform_ik_k(float* __restrict__ ik,
    const float* __restrict__ knw, const float* __restrict__ knb,
    const float* __restrict__ cosb, const float* __restrict__ sinb)
{
    int row = blockIdx.x;
    int t = row / IH_;
    int tid = threadIdx.x;
    __shared__ float s[128], w2[128], red[128];
    float v = ik[(long)row * 128 + tid];
    red[tid] = v; __syncthreads();
    for (int off = 64; off; off >>= 1) { if (tid < off) red[tid] += red[tid + off]; __syncthreads(); }
    float m = red[0] / 128.f; __syncthreads();
    float d = v - m;
    red[tid] = d * d; __syncthreads();
    for (int off = 64; off; off >>= 1) { if (tid < off) red[tid] += red[tid + off]; __syncthreads(); }
    float var = red[0] / 128.f;
    s[tid] = d * rsqrtf(var + 1e-5f) * knw[tid] + knb[tid];
    __syncthreads();
    rope_rotate_128(s, w2, tid, t, cosb, sinb);
    ik[(long)row * 128 + tid] = w2[tid];
}

__global__ __launch_bounds__(256) void transform_kv_k(const float* __restrict__ kva,
    float* __restrict__ kvkey, const float* __restrict__ kvnw,
    const float* __restrict__ cosb, const float* __restrict__ sinb)
{
    int t = blockIdx.x, tid = threadIdx.x;
    const float* a = kva + (long)t * CKV_;
    float* o = kvkey + (long)t * CKV_;
    float v0 = a[tid], v1 = a[tid + 256];
    __shared__ float red[256];
    __shared__ float rsh;
    red[tid] = v0 * v0 + v1 * v1; __syncthreads();
    for (int off = 128; off; off >>= 1) { if (tid < off) red[tid] += red[tid + off]; __syncthreads(); }
    if (tid == 0) rsh = rsqrtf(red[0] / (float)KVLR_ + 1e-6f);
    __syncthreads();
    float rs = rsh;
    o[tid]       = v0 * rs * kvnw[tid];
    o[tid + 256] = v1 * rs * kvnw[tid + 256];
    if (tid < 32) {
        float x1 = a[512 + tid], x2 = a[544 + tid];
        float c = cosb[t * 32 + tid], sn = sinb[t * 32 + tid];
        o[512 + tid] = x1 * c - x2 * sn;
        o[544 + tid] = x1 * sn + x2 * c;
    }
}

__global__ __launch_bounds__(64) void qpe_k(const float* __restrict__ q, float* __restrict__ qkey,
    const float* __restrict__ cosb, const float* __restrict__ sinb)
{
    int row = blockIdx.x * 2 + (threadIdx.x >> 5);
    int i = threadIdx.x & 31;
    int t = row / H_;
    const float* qp = q + (long)row * QKD_ + NOPE_;
    float x1 = qp[i], x2 = qp[i + 32];
    float c = cosb[t * 32 + i], sn = sinb[t * 32 + i];
    float* o = qkey + (long)row * CKV_ + 512;
    o[i]      = x1 * c - x2 * sn;
    o[i + 32] = x1 * sn + x2 * c;
}

// ---------------------------------------------------------------------------
// Indexer score v2: 64x64 tiles, BK=32 float4 staging, b128 reads, 4x4 micro.
// ---------------------------------------------------------------------------
__global__ __launch_bounds__(256) void score2_k(const float* __restrict__ iq,
    const float* __restrict__ ik, const float* __restrict__ wtok, float* __restrict__ score)
{
    const int bt = blockIdx.y, bs = blockIdx.x;
    if (bs > bt) return;
    __shared__ float As[32][68];
    __shared__ float Bs[32][68];
    const int tid = threadIdx.x;
    const int tx = tid & 15, ty = tid >> 4;
    const int t0 = bt * 64, s0 = bs * 64;
    const int um = tid >> 3, uu = tid & 7;
    const float4* iq4 = (const float4*)iq;
    const float4* ik4 = (const float4*)ik;
    float accf[4][4] = {};

    for (int h = 0; h < IH_; ++h) {
        float acch[4][4] = {};
        #pragma unroll
        for (int k0 = 0; k0 < ID_; k0 += 32) {
            __syncthreads();
            #pragma unroll
            for (int rep = 0; rep < 2; ++rep) {
                int m = um + 32 * rep;
                float4 a = iq4[((long)(t0 + m) * IH_ + h) * 32 + (k0 >> 2) + uu];
                As[4*uu+0][m] = a.x; As[4*uu+1][m] = a.y; As[4*uu+2][m] = a.z; As[4*uu+3][m] = a.w;
                float4 b = ik4[((long)(s0 + m) * IH_ + h) * 32 + (k0 >> 2) + uu];
                Bs[4*uu+0][m] = b.x; Bs[4*uu+1][m] = b.y; Bs[4*uu+2][m] = b.z; Bs[4*uu+3][m] = b.w;
            }
            __syncthreads();
            #pragma unroll
            for (int kk = 0; kk < 32; ++kk) {
                const float4 a4 = *(const float4*)&As[kk][4 * ty];
                const float4 b4 = *(const float4*)&Bs[kk][4 * tx];
                const float af[4] = {a4.x, a4.y, a4.z, a4.w};
                const float bf[4] = {b4.x, b4.y, b4.z, b4.w};
                #pragma unroll
                for (int i = 0; i < 4; ++i)
                    #pragma unroll
                    for (int j = 0; j < 4; ++j) acch[i][j] += af[i] * bf[j];
            }
        }
        #pragma unroll
        for (int i = 0; i < 4; ++i) {
            float wv = wtok[(long)(t0 + 4 * ty + i) * IH_ + h];
            #pragma unroll
            for (int j = 0; j < 4; ++j) accf[i][j] += fmaxf(acch[i][j], 0.f) * wv;
        }
    }
    #pragma unroll
    for (int i = 0; i < 4; ++i) {
        float4 o = make_float4(accf[i][0], accf[i][1], accf[i][2], accf[i][3]);
        *(float4*)&score[(long)(t0 + 4 * ty + i) * T_ + s0 + 4 * tx] = o;
    }
}

// ---------------------------------------------------------------------------
// Top-256 per row via bitonic sort (ties -> lower index, matches jax top_k)
// ---------------------------------------------------------------------------
__global__ __launch_bounds__(512) void topk_k(const float* __restrict__ score, int* __restrict__ topk)
{
    int t = blockIdx.x, tid = threadIdx.x;
    __shared__ float v[1024];
    __shared__ int ix[1024];
    for (int i = tid; i < 1024; i += 512) {
        v[i] = (i <= t) ? score[(long)t * T_ + i] : -INFINITY;
        ix[i] = i;
    }
    __syncthreads();
    for (int k = 2; k <= 1024; k <<= 1) {
        for (int j = k >> 1; j > 0; j >>= 1) {
            for (int i = tid; i < 1024; i += 512) {
                int l = i ^ j;
                if (l > i) {
                    bool up = ((i & k) == 0);
                    float vi = v[i], vl = v[l];
                    int xi = ix[i], xl = ix[l];
                    bool iBetter = (vi > vl) || (vi == vl && xi < xl);
                    bool doSwap = up ? !iBetter : iBetter;
                    if (doSwap) { v[i] = vl; v[l] = vi; ix[i] = xl; ix[l] = xi; }
                }
            }
            __syncthreads();
        }
    }
    if (tid < 256) topk[(long)t * TOPK_ + tid] = ix[tid];
}

// ---------------------------------------------------------------------------
// Attention v2: one block per token t, all 16 heads.
//   Phase A: logits L[16][256] = qk(16x576) . selT, c-tiled LDS staging.
//   Softmax: wave-local (wave = 4 heads x 64 key-quads), shuffle reduce.
//   Phase B: out_latent[16][512] = P(16x256) . sel[:, :512], k-tiled staging.
// LDS union: phase A {qk 36864B | KsT 16640B} / phase B {PT 20480B | Sel 33280B}
// Thread map: hq = tid>>6 (wave id -> 4 heads), kq = tid&63.
// ---------------------------------------------------------------------------
__global__ __launch_bounds__(256) void attn2_k(
    const float* __restrict__ qkey, const float* __restrict__ kvkey,
    const int* __restrict__ topkp, float* __restrict__ olat)
{
    __shared__ float U[13440];
    __shared__ int kidxs[256];
    const int t = blockIdx.x, tid = threadIdx.x;
    const int hq = tid >> 6, kq = tid & 63;

    float4* qk4 = (float4*)U;          // [16][144] float4 (per-h row = 144 float4)
    float*  KsT = U + 9216;            // [16][260]  (c-local rows, k cols)
    float*  PT  = U;                   // [256][20]  (k rows, h cols) -- phase B
    float*  Sel = U + 5120;            // [32][260]  (k-local rows, c cols) -- phase B
    const float4* qkey4  = (const float4*)qkey;
    const float4* kvkey4 = (const float4*)kvkey;

    kidxs[tid] = topkp[(long)t * TOPK_ + tid];
    for (int e = tid; e < 2304; e += 256)
        qk4[e] = qkey4[(long)t * 2304 + e];
    __syncthreads();

    int  myki[4]; bool vld[4];
    #pragma unroll
    for (int j = 0; j < 4; ++j) { myki[j] = kidxs[kq * 4 + j]; vld[j] = (myki[j] <= t); }

    // ---- Phase A: logits ----
    float acc[4][4] = {};
    for (int c0 = 0; c0 < CKV_; c0 += 16) {
        __syncthreads();
        {
            const int u = tid & 3, kr0 = tid >> 2;
            #pragma unroll
            for (int rep = 0; rep < 4; ++rep) {
                int k = kr0 + 64 * rep;
                float4 v = kvkey4[(long)kidxs[k] * 144 + (c0 >> 2) + u];
                KsT[(4*u+0)*260 + k] = v.x;
                KsT[(4*u+1)*260 + k] = v.y;
                KsT[(4*u+2)*260 + k] = v.z;
                KsT[(4*u+3)*260 + k] = v.w;
            }
        }
        __syncthreads();
        #pragma unroll
        for (int cg = 0; cg < 4; ++cg) {
            float qs[4][4];
            #pragma unroll
            for (int i = 0; i < 4; ++i) {
                float4 qv = qk4[(4*hq + i) * 144 + (c0 >> 2) + cg];
                qs[i][0] = qv.x; qs[i][1] = qv.y; qs[i][2] = qv.z; qs[i][3] = qv.w;
            }
            #pragma unroll
            for (int j4 = 0; j4 < 4; ++j4) {
                const float4 ks = *(const float4*)&KsT[(cg*4 + j4)*260 + 4*kq];
                #pragma unroll
                for (int i = 0; i < 4; ++i) {
                    acc[i][0] += qs[i][j4] * ks.x;
                    acc[i][1] += qs[i][j4] * ks.y;
                    acc[i][2] += qs[i][j4] * ks.z;
                    acc[i][3] += qs[i][j4] * ks.w;
                }
            }
        }
    }
    __syncthreads();   // all phase-A LDS reads done before PT overwrites qk region

    // ---- Softmax (per h row; row spans exactly this wave) ----
    float p[4][4];
    #pragma unroll
    for (int i = 0; i < 4; ++i) {
        float l[4]; float lm = -INFINITY;
        #pragma unroll
        for (int j = 0; j < 4; ++j) {
            l[j] = vld[j] ? acc[i][j] * SCALE_LOG : -INFINITY;
            lm = fmaxf(lm, l[j]);
        }
        for (int off = 32; off; off >>= 1) lm = fmaxf(lm, __shfl_xor(lm, off, 64));
        float s = 0.f;
        #pragma unroll
        for (int j = 0; j < 4; ++j) {
            float e = vld[j] ? expf(l[j] - lm) : 0.f;
            p[i][j] = e; s += e;
        }
        for (int off = 32; off; off >>= 1) s += __shfl_xor(s, off, 64);
        float inv = 1.f / s;
        #pragma unroll
        for (int j = 0; j < 4; ++j) p[i][j] *= inv;
    }
    #pragma unroll
    for (int j = 0; j < 4; ++j)
        #pragma unroll
        for (int i = 0; i < 4; ++i)
            PT[(4*kq + j) * 20 + 4*hq + i] = p[i][j];
    __syncthreads();

    // ---- Phase B: out_latent ----
    for (int c0 = 0; c0 < KVLR_; c0 += 256) {
        float a2[4][4] = {};
        for (int k0 = 0; k0 < TOPK_; k0 += 32) {
            __syncthreads();
            #pragma unroll
            for (int rep = 0; rep < 8; ++rep) {
                int e = rep * 256 + tid;
                int kk = e >> 6, u = e & 63;
                float4 v = kvkey4[(long)kidxs[k0 + kk] * 144 + (c0 >> 2) + u];
                *(float4*)&Sel[kk * 260 + 4 * u] = v;
            }
            __syncthreads();
            #pragma unroll
            for (int kk = 0; kk < 32; ++kk) {
                const float4 pt = *(const float4*)&PT[(k0 + kk) * 20 + 4 * hq];
                const float4 sv = *(const float4*)&Sel[kk * 260 + 4 * kq];
                const float pf[4] = {pt.x, pt.y, pt.z, pt.w};
                #pragma unroll
                for (int i = 0; i < 4; ++i) {
                    a2[i][0] += pf[i] * sv.x;
                    a2[i][1] += pf[i] * sv.y;
                    a2[i][2] += pf[i] * sv.z;
                    a2[i][3] += pf[i] * sv.w;
                }
            }
        }
        #pragma unroll
        for (int i = 0; i < 4; ++i) {
            float4 o = make_float4(a2[i][0], a2[i][1], a2[i][2], a2[i][3]);
            *(float4*)&olat[((long)t * H_ + 4*hq + i) * 512 + c0 + 4 * kq] = o;
        }
    }
}

// ---------------------------------------------------------------------------
extern "C" void kernel_launch(void* const* d_in, const int* in_sizes, int n_in,
                              void* d_out, int out_size, void* d_ws, size_t ws_size,
                              hipStream_t stream)
{
    const float* x          = (const float*)d_in[0];
    const float* cosb       = (const float*)d_in[1];
    const float* sinb       = (const float*)d_in[2];
    const float* wq_a       = (const float*)d_in[3];
    const float* q_norm_w   = (const float*)d_in[4];
    const float* wq_b       = (const float*)d_in[5];
    const float* wkv_a      = (const float*)d_in[6];
    const float* kv_norm_w  = (const float*)d_in[7];
    const float* wkv_b      = (const float*)d_in[8];
    const float* wo         = (const float*)d_in[9];
    const float* iq_norm_w  = (const float*)d_in[10];
    const float* iwq_b      = (const float*)d_in[11];
    const float* iwk        = (const float*)d_in[12];
    const float* k_norm_w   = (const float*)d_in[13];
    const float* k_norm_b   = (const float*)d_in[14];
    const float* wproj      = (const float*)d_in[15];
    float* out = (float*)d_out;

    // workspace layout (float offsets); union region reused by out_latent
    float* ws    = (float*)d_ws;
    float* qr    = ws;                      // 1,048,576
    float* rstd  = ws + 1048576;            // 1,024
    float* wtok  = ws + 1049600;            // 16,384
    float* kvkey = ws + 1065984;            // 589,824
    int*   topk  = (int*)(ws + 1655808);    // 262,144 ints
    float* qkey  = ws + 1917952;            // 9,437,184
    float* outv  = ws + 11355136;           // 2,097,152
    float* U0    = ws + 13452288;           // union region (8,978,432 floats)
    float* iq    = U0;                      // 2,097,152   (dead after score2)
    float* ik    = U0 + 2097152;            // 2,097,152   (dead after score2)
    float* kva   = U0 + 4194304;            // 589,824     (dead after transform_kv)
    float* q     = U0 + 4784128;            // 3,145,728   (dead after q_nope_proj)
    float* score = U0 + 7929856;            // 1,048,576   (dead after topk)
    float* olat  = U0;                      // 8,388,608   (aliases all of the above)

    // 1. qr = x @ wq_a.T
    gemm_nt64_k<<<dim3(QLR_/64, T_/64, 1), 256, 0, stream>>>(
        x, wq_a, qr, 0, 0, 0, DIM_, DIM_, QLR_, DIM_, 1.f, nullptr, nullptr);
    // 2. rstd(qr)
    rstd_k<<<T_, 256, 0, stream>>>(qr, rstd);
    // 3. wtok = x @ wproj.T * scale   (N=16, guarded kernel)
    gemm_nt_k<<<dim3(1, T_/64), 256, 0, stream>>>(x, wproj, wtok, T_, IH_, DIM_, SCALE_W, nullptr, nullptr);
    // 4. ikraw = x @ iwk.T
    gemm_nt64_k<<<dim3(IH_*ID_/64, T_/64, 1), 256, 0, stream>>>(
        x, iwk, ik, 0, 0, 0, DIM_, DIM_, IH_*ID_, DIM_, 1.f, nullptr, nullptr);
    // 5. kva = x @ wkv_a.T
    gemm_nt64_k<<<dim3(CKV_/64, T_/64, 1), 256, 0, stream>>>(
        x, wkv_a, kva, 0, 0, 0, DIM_, DIM_, CKV_, DIM_, 1.f, nullptr, nullptr);
    // 6. iq = rmsnorm(qr) @ iwq_b.T
    gemm_nt64_k<<<dim3(IH_*ID_/64, T_/64, 1), 256, 0, stream>>>(
        qr, iwq_b, iq, 0, 0, 0, QLR_, QLR_, IH_*ID_, QLR_, 1.f, iq_norm_w, rstd);
    // 7. q = rmsnorm(qr) @ wq_b.T
    gemm_nt64_k<<<dim3(H_*QKD_/64, T_/64, 1), 256, 0, stream>>>(
        qr, wq_b, q, 0, 0, 0, QLR_, QLR_, H_*QKD_, QLR_, 1.f, q_norm_w, rstd);
    // 8-10. per-row transforms
    transform_iq_k<<<T_*IH_, 128, 0, stream>>>(iq, cosb, sinb);
    transform_ik_k<<<T_*IH_, 128, 0, stream>>>(ik, k_norm_w, k_norm_b, cosb, sinb);
    transform_kv_k<<<T_, 256, 0, stream>>>(kva, kvkey, kv_norm_w, cosb, sinb);
    // 11. q_key rope part
    qpe_k<<<T_*H_/2, 64, 0, stream>>>(q, qkey, cosb, sinb);
    // 12. q_key nope part (batched NN)
    gemm_nn_b_k<<<dim3(KVLR_/64, T_/64, H_), 256, 0, stream>>>(
        q, wkv_b, qkey,
        (long)QKD_, (long)(NOPE_+VD_)*KVLR_, (long)CKV_,
        H_*QKD_, KVLR_, H_*CKV_, T_, KVLR_, NOPE_);
    // 13. indexer scores
    score2_k<<<dim3(T_/64, T_/64), 256, 0, stream>>>(iq, ik, wtok, score);
    // 14. top-256
    topk_k<<<T_, 512, 0, stream>>>(score, topk);
    // 15. attention -> out_latent
    attn2_k<<<T_, 256, 0, stream>>>(qkey, kvkey, topk, olat);
    // 15b. out_v = out_latent @ w_v^T (batched NT)
    gemm_nt64_k<<<dim3(VD_/64, T_/64, H_), 256, 0, stream>>>(
        olat, wkv_b + (long)NOPE_*KVLR_, outv,
        (long)KVLR_, (long)(NOPE_+VD_)*KVLR_, (long)VD_,
        H_*KVLR_, KVLR_, H_*VD_, KVLR_, 1.f, nullptr, nullptr);
    // 16. out = outv @ wo.T
    gemm_nt64_k<<<dim3(DIM_/64, T_/64, 1), 256, 0, stream>>>(
        outv, wo, out, 0, 0, 0, H_*VD_, H_*VD_, DIM_, H_*VD_, 1.f, nullptr, nullptr);

    (void)in_sizes; (void)n_in; (void)out_size; (void)ws_size;
}

// Round 3
// 1229.169 us; speedup vs baseline: 3.2890x; 1.2780x over previous
//
#include <hip/hip_runtime.h>
#include <hip/hip_bf16.h>
#include <math.h>

// Problem constants
#define T_     1024
#define DIM_   2048
#define H_     16
#define QLR_   1024
#define KVLR_  512
#define NOPE_  128
#define ROPE_  64
#define VD_    128
#define QKD_   192   // NOPE+ROPE
#define IH_    16
#define ID_    128
#define TOPK_  256
#define CKV_   576   // KVLR + ROPE

#define SCALE_W    0.022097086912079608f   // IH^-0.5 * ID^-0.5
#define SCALE_LOG  0.07216878364870323f    // QKD^-0.5

typedef short bfrag __attribute__((ext_vector_type(8)));   // 8 bf16 = 4 VGPRs
typedef float ffrag __attribute__((ext_vector_type(4)));   // 4 fp32 acc

__device__ __forceinline__ unsigned short f2bf(float f) {
    union { __hip_bfloat16 h; unsigned short u; } c; c.h = __float2bfloat16(f); return c.u;
}
__device__ __forceinline__ float bf2f(unsigned short u) {
    union { unsigned short u; __hip_bfloat16 h; } c; c.u = u; return __bfloat162float(c.h);
}

// ---------------------------------------------------------------------------
// fp32 -> bf16 cast, optional hi/lo split and per-row/col scaling.
// n must be a multiple of 1024. If colw/rowscale given, Kc is the row length.
// ---------------------------------------------------------------------------
__global__ __launch_bounds__(256) void cast_hl_k(
    const float* __restrict__ in, unsigned short* __restrict__ hi,
    unsigned short* __restrict__ lo, long n,
    const float* __restrict__ colw, const float* __restrict__ rowscale, int Kc)
{
    long base = ((long)blockIdx.x * 256 + threadIdx.x) * 4;
    if (base >= n) return;
    float4 v = *(const float4*)(in + base);
    float s[4] = {v.x, v.y, v.z, v.w};
    if (colw) {
        int col = (int)(base % Kc);
        float4 cw = *(const float4*)(colw + col);
        s[0] *= cw.x; s[1] *= cw.y; s[2] *= cw.z; s[3] *= cw.w;
    }
    if (rowscale) {
        float r = rowscale[base / Kc];
        s[0] *= r; s[1] *= r; s[2] *= r; s[3] *= r;
    }
    ushort4 h4;
    h4.x = f2bf(s[0]); h4.y = f2bf(s[1]); h4.z = f2bf(s[2]); h4.w = f2bf(s[3]);
    *(ushort4*)(hi + base) = h4;
    if (lo) {
        ushort4 l4;
        l4.x = f2bf(s[0] - bf2f(h4.x));
        l4.y = f2bf(s[1] - bf2f(h4.y));
        l4.z = f2bf(s[2] - bf2f(h4.z));
        l4.w = f2bf(s[3] - bf2f(h4.w));
        *(ushort4*)(lo + base) = l4;
    }
}

// ---------------------------------------------------------------------------
// Transpose-cast w_k: wkT[h][c][d] = bf16(wkv_b[(h*256+d)*512 + c]), d<128, c<512
// ---------------------------------------------------------------------------
__global__ __launch_bounds__(256) void tcast_k(const float* __restrict__ in,
                                               unsigned short* __restrict__ out)
{
    int h = blockIdx.z, c0 = blockIdx.x * 32, d0 = blockIdx.y * 32;
    __shared__ float t[32][33];
    int tx = threadIdx.x & 31, ty = threadIdx.x >> 5;   // ty 0..7
    #pragma unroll
    for (int i = 0; i < 4; ++i)
        t[ty + i * 8][tx] = in[(long)(h * 256 + d0 + ty + i * 8) * 512 + c0 + tx];
    __syncthreads();
    #pragma unroll
    for (int i = 0; i < 4; ++i)
        out[((long)h * 512 + c0 + ty + i * 8) * 128 + d0 + tx] = f2bf(t[tx][ty + i * 8]);
}

// ---------------------------------------------------------------------------
// MFMA bf16 NT GEMM: C[m,n] (+)= sum_k A[m,k]*B[n,k], A/B bf16, C fp32.
// Tile 128x128, BK=32, 4 waves each 64x64 (4x4 frags of 16x16x32).
// M multiple of 128 (no guard); N guarded (staging clamp + store guard).
// K multiple of 32. Batched via blockIdx.z (element strides sA/sB/sC).
// beta=1: accumulate into existing C.
// ---------------------------------------------------------------------------
__global__ __launch_bounds__(256) void gemm_bt_mfma_k(
    const unsigned short* __restrict__ A, const unsigned short* __restrict__ B,
    float* __restrict__ C, long sA, long sB, long sC,
    int lda, int ldb, int ldc, int N, int K, int beta)
{
    A += (long)blockIdx.z * sA;
    B += (long)blockIdx.z * sB;
    C += (long)blockIdx.z * sC;
    __shared__ unsigned short As[128 * 40];
    __shared__ unsigned short Bs[128 * 40];
    const int tid = threadIdx.x;
    const int bm = blockIdx.y * 128, bn = blockIdx.x * 128;
    const int wave = tid >> 6, lane = tid & 63;
    const int wm = (wave >> 1) * 64, wn = (wave & 1) * 64;
    const int lm = lane & 15, quad = lane >> 4;

    ffrag acc[4][4];
    if (beta) {
        #pragma unroll
        for (int mi = 0; mi < 4; ++mi)
            #pragma unroll
            for (int ni = 0; ni < 4; ++ni) {
                int n = bn + wn + ni * 16 + lm;
                int mb = bm + wm + mi * 16 + quad * 4;
                #pragma unroll
                for (int r = 0; r < 4; ++r)
                    acc[mi][ni][r] = (n < N) ? C[(long)(mb + r) * ldc + n] : 0.f;
            }
    } else {
        #pragma unroll
        for (int mi = 0; mi < 4; ++mi)
            #pragma unroll
            for (int ni = 0; ni < 4; ++ni)
                #pragma unroll
                for (int r = 0; r < 4; ++r) acc[mi][ni][r] = 0.f;
    }

    const int srow = tid >> 1, shalf = tid & 1;
    const long aoff = (long)(bm + srow) * lda + shalf * 16;
    int brow = bn + srow; if (brow > N - 1) brow = N - 1;
    const long boff = (long)brow * ldb + shalf * 16;
    unsigned short* la = As + srow * 40 + shalf * 16;
    unsigned short* lb = Bs + srow * 40 + shalf * 16;

    for (int k0 = 0; k0 < K; k0 += 32) {
        __syncthreads();
        uint4 va0 = *(const uint4*)(A + aoff + k0);
        uint4 va1 = *(const uint4*)(A + aoff + k0 + 8);
        uint4 vb0 = *(const uint4*)(B + boff + k0);
        uint4 vb1 = *(const uint4*)(B + boff + k0 + 8);
        *(uint4*)la = va0; *(uint4*)(la + 8) = va1;
        *(uint4*)lb = vb0; *(uint4*)(lb + 8) = vb1;
        __syncthreads();
        bfrag af[4], bf[4];
        #pragma unroll
        for (int mi = 0; mi < 4; ++mi)
            af[mi] = *(const bfrag*)(As + (wm + mi * 16 + lm) * 40 + quad * 8);
        #pragma unroll
        for (int ni = 0; ni < 4; ++ni)
            bf[ni] = *(const bfrag*)(Bs + (wn + ni * 16 + lm) * 40 + quad * 8);
        #pragma unroll
        for (int mi = 0; mi < 4; ++mi)
            #pragma unroll
            for (int ni = 0; ni < 4; ++ni)
                acc[mi][ni] = __builtin_amdgcn_mfma_f32_16x16x32_bf16(
                    af[mi], bf[ni], acc[mi][ni], 0, 0, 0);
    }

    #pragma unroll
    for (int mi = 0; mi < 4; ++mi)
        #pragma unroll
        for (int ni = 0; ni < 4; ++ni) {
            int n = bn + wn + ni * 16 + lm;
            if (n < N) {
                int mb = bm + wm + mi * 16 + quad * 4;
                #pragma unroll
                for (int r = 0; r < 4; ++r)
                    C[(long)(mb + r) * ldc + n] = acc[mi][ni][r];
            }
        }
}

// ---------------------------------------------------------------------------
// Fused wtok: wtok[t,h] = dot(x[t,:], wproj[h,:]) * SCALE_W
// ---------------------------------------------------------------------------
__global__ __launch_bounds__(256) void wtok_k(const float* __restrict__ x,
    const float* __restrict__ wproj, float* __restrict__ wtok)
{
    int t = blockIdx.x, tid = threadIdx.x;
    __shared__ float xs[DIM_];
    for (int c = tid; c < DIM_; c += 256) xs[c] = x[(long)t * DIM_ + c];
    __syncthreads();
    int wave = tid >> 6, lane = tid & 63;
    #pragma unroll
    for (int i = 0; i < 4; ++i) {
        int h = wave * 4 + i;
        float s = 0.f;
        for (int c = lane; c < DIM_; c += 64) s += xs[c] * wproj[(long)h * DIM_ + c];
        for (int off = 32; off; off >>= 1) s += __shfl_xor(s, off, 64);
        if (lane == 0) wtok[(long)t * IH_ + h] = s * SCALE_W;
    }
}

// ---------------------------------------------------------------------------
__global__ __launch_bounds__(256) void rstd_k(const float* __restrict__ qr, float* __restrict__ rstd)
{
    int t = blockIdx.x, tid = threadIdx.x;
    float s = 0.f;
    for (int c = tid; c < QLR_; c += 256) { float v = qr[(long)t * QLR_ + c]; s += v * v; }
    __shared__ float red[256];
    red[tid] = s; __syncthreads();
    for (int off = 128; off; off >>= 1) { if (tid < off) red[tid] += red[tid + off]; __syncthreads(); }
    if (tid == 0) rstd[t] = rsqrtf(red[0] / (float)QLR_ + 1e-6f);
}

// ---------------------------------------------------------------------------
__device__ __forceinline__ void rope_rotate_128(float* s, float* w2, int tid, int t,
    const float* __restrict__ cosb, const float* __restrict__ sinb)
{
    float n1 = 0.f, n2 = 0.f;
    if (tid < 32) {
        float x1 = s[tid], x2 = s[tid + 32];
        float c = cosb[t * 32 + tid], sn = sinb[t * 32 + tid];
        n1 = x1 * c - x2 * sn;
        n2 = x1 * sn + x2 * c;
    }
    __syncthreads();
    if (tid < 32) { s[tid] = n1; s[tid + 32] = n2; }
    __syncthreads();
    const int g = tid >> 6, p = tid & 63;
    w2[tid] = s[((1 - g) << 6) + p];
    __syncthreads();
    #pragma unroll
    for (int h = 1; h < 64; h <<= 1) {
        float a = w2[tid], b = w2[(g << 6) + (p ^ h)];
        __syncthreads();
        w2[tid] = (p & h) ? (b - a) : (a + b);
        __syncthreads();
    }
}

__global__ __launch_bounds__(128) void transform_iq_k(float* __restrict__ iq,
    const float* __restrict__ cosb, const float* __restrict__ sinb)
{
    int row = blockIdx.x;
    int t = row / IH_;
    int tid = threadIdx.x;
    __shared__ float s[128], w2[128];
    s[tid] = iq[(long)row * 128 + tid];
    __syncthreads();
    rope_rotate_128(s, w2, tid, t, cosb, sinb);
    iq[(long)row * 128 + tid] = w2[tid];
}

__global__ __launch_bounds__(128) void transform_ik_k(float* __restrict__ ik,
    const float* __restrict__ knw, const float* __restrict__ knb,
    const float* __restrict__ cosb, const float* __restrict__ sinb)
{
    int row = blockIdx.x;
    int t = row / IH_;
    int tid = threadIdx.x;
    __shared__ float s[128], w2[128], red[128];
    float v = ik[(long)row * 128 + tid];
    red[tid] = v; __syncthreads();
    for (int off = 64; off; off >>= 1) { if (tid < off) red[tid] += red[tid + off]; __syncthreads(); }
    float m = red[0] / 128.f; __syncthreads();
    float d = v - m;
    red[tid] = d * d; __syncthreads();
    for (int off = 64; off; off >>= 1) { if (tid < off) red[tid] += red[tid + off]; __syncthreads(); }
    float var = red[0] / 128.f;
    s[tid] = d * rsqrtf(var + 1e-5f) * knw[tid] + knb[tid];
    __syncthreads();
    rope_rotate_128(s, w2, tid, t, cosb, sinb);
    ik[(long)row * 128 + tid] = w2[tid];
}

__global__ __launch_bounds__(256) void transform_kv_k(const float* __restrict__ kva,
    float* __restrict__ kvkey, const float* __restrict__ kvnw,
    const float* __restrict__ cosb, const float* __restrict__ sinb)
{
    int t = blockIdx.x, tid = threadIdx.x;
    const float* a = kva + (long)t * CKV_;
    float* o = kvkey + (long)t * CKV_;
    float v0 = a[tid], v1 = a[tid + 256];
    __shared__ float red[256];
    __shared__ float rsh;
    red[tid] = v0 * v0 + v1 * v1; __syncthreads();
    for (int off = 128; off; off >>= 1) { if (tid < off) red[tid] += red[tid + off]; __syncthreads(); }
    if (tid == 0) rsh = rsqrtf(red[0] / (float)KVLR_ + 1e-6f);
    __syncthreads();
    float rs = rsh;
    o[tid]       = v0 * rs * kvnw[tid];
    o[tid + 256] = v1 * rs * kvnw[tid + 256];
    if (tid < 32) {
        float x1 = a[512 + tid], x2 = a[544 + tid];
        float c = cosb[t * 32 + tid], sn = sinb[t * 32 + tid];
        o[512 + tid] = x1 * c - x2 * sn;
        o[544 + tid] = x1 * sn + x2 * c;
    }
}

__global__ __launch_bounds__(64) void qpe_k(const float* __restrict__ q, float* __restrict__ qkey,
    const float* __restrict__ cosb, const float* __restrict__ sinb)
{
    int row = blockIdx.x * 2 + (threadIdx.x >> 5);
    int i = threadIdx.x & 31;
    int t = row / H_;
    const float* qp = q + (long)row * QKD_ + NOPE_;
    float x1 = qp[i], x2 = qp[i + 32];
    float c = cosb[t * 32 + i], sn = sinb[t * 32 + i];
    float* o = qkey + (long)row * CKV_ + 512;
    o[i]      = x1 * c - x2 * sn;
    o[i + 32] = x1 * sn + x2 * c;
}

// ---------------------------------------------------------------------------
// Indexer score (fp32, topk-critical)
// ---------------------------------------------------------------------------
__global__ __launch_bounds__(256) void score2_k(const float* __restrict__ iq,
    const float* __restrict__ ik, const float* __restrict__ wtok, float* __restrict__ score)
{
    const int bt = blockIdx.y, bs = blockIdx.x;
    if (bs > bt) return;
    __shared__ float As[32][68];
    __shared__ float Bs[32][68];
    const int tid = threadIdx.x;
    const int tx = tid & 15, ty = tid >> 4;
    const int t0 = bt * 64, s0 = bs * 64;
    const int um = tid >> 3, uu = tid & 7;
    const float4* iq4 = (const float4*)iq;
    const float4* ik4 = (const float4*)ik;
    float accf[4][4] = {};

    for (int h = 0; h < IH_; ++h) {
        float acch[4][4] = {};
        #pragma unroll
        for (int k0 = 0; k0 < ID_; k0 += 32) {
            __syncthreads();
            #pragma unroll
            for (int rep = 0; rep < 2; ++rep) {
                int m = um + 32 * rep;
                float4 a = iq4[((long)(t0 + m) * IH_ + h) * 32 + (k0 >> 2) + uu];
                As[4*uu+0][m] = a.x; As[4*uu+1][m] = a.y; As[4*uu+2][m] = a.z; As[4*uu+3][m] = a.w;
                float4 b = ik4[((long)(s0 + m) * IH_ + h) * 32 + (k0 >> 2) + uu];
                Bs[4*uu+0][m] = b.x; Bs[4*uu+1][m] = b.y; Bs[4*uu+2][m] = b.z; Bs[4*uu+3][m] = b.w;
            }
            __syncthreads();
            #pragma unroll
            for (int kk = 0; kk < 32; ++kk) {
                const float4 a4 = *(const float4*)&As[kk][4 * ty];
                const float4 b4 = *(const float4*)&Bs[kk][4 * tx];
                const float af[4] = {a4.x, a4.y, a4.z, a4.w};
                const float bf[4] = {b4.x, b4.y, b4.z, b4.w};
                #pragma unroll
                for (int i = 0; i < 4; ++i)
                    #pragma unroll
                    for (int j = 0; j < 4; ++j) acch[i][j] += af[i] * bf[j];
            }
        }
        #pragma unroll
        for (int i = 0; i < 4; ++i) {
            float wv = wtok[(long)(t0 + 4 * ty + i) * IH_ + h];
            #pragma unroll
            for (int j = 0; j < 4; ++j) accf[i][j] += fmaxf(acch[i][j], 0.f) * wv;
        }
    }
    #pragma unroll
    for (int i = 0; i < 4; ++i) {
        float4 o = make_float4(accf[i][0], accf[i][1], accf[i][2], accf[i][3]);
        *(float4*)&score[(long)(t0 + 4 * ty + i) * T_ + s0 + 4 * tx] = o;
    }
}

// ---------------------------------------------------------------------------
// Top-256 per row via bitonic sort (ties -> lower index, matches jax top_k)
// ---------------------------------------------------------------------------
__global__ __launch_bounds__(512) void topk_k(const float* __restrict__ score, int* __restrict__ topk)
{
    int t = blockIdx.x, tid = threadIdx.x;
    __shared__ float v[1024];
    __shared__ int ix[1024];
    for (int i = tid; i < 1024; i += 512) {
        v[i] = (i <= t) ? score[(long)t * T_ + i] : -INFINITY;
        ix[i] = i;
    }
    __syncthreads();
    for (int k = 2; k <= 1024; k <<= 1) {
        for (int j = k >> 1; j > 0; j >>= 1) {
            for (int i = tid; i < 1024; i += 512) {
                int l = i ^ j;
                if (l > i) {
                    bool up = ((i & k) == 0);
                    float vi = v[i], vl = v[l];
                    int xi = ix[i], xl = ix[l];
                    bool iBetter = (vi > vl) || (vi == vl && xi < xl);
                    bool doSwap = up ? !iBetter : iBetter;
                    if (doSwap) { v[i] = vl; v[l] = vi; ix[i] = xl; ix[l] = xi; }
                }
            }
            __syncthreads();
        }
    }
    if (tid < 256) topk[(long)t * TOPK_ + tid] = ix[tid];
}

// ---------------------------------------------------------------------------
// Attention: one block per token t, all 16 heads (fp32)
// ---------------------------------------------------------------------------
__global__ __launch_bounds__(256) void attn2_k(
    const float* __restrict__ qkey, const float* __restrict__ kvkey,
    const int* __restrict__ topkp, float* __restrict__ olat)
{
    __shared__ float U[13440];
    __shared__ int kidxs[256];
    const int t = blockIdx.x, tid = threadIdx.x;
    const int hq = tid >> 6, kq = tid & 63;

    float4* qk4 = (float4*)U;
    float*  KsT = U + 9216;
    float*  PT  = U;
    float*  Sel = U + 5120;
    const float4* qkey4  = (const float4*)qkey;
    const float4* kvkey4 = (const float4*)kvkey;

    kidxs[tid] = topkp[(long)t * TOPK_ + tid];
    for (int e = tid; e < 2304; e += 256)
        qk4[e] = qkey4[(long)t * 2304 + e];
    __syncthreads();

    int  myki[4]; bool vld[4];
    #pragma unroll
    for (int j = 0; j < 4; ++j) { myki[j] = kidxs[kq * 4 + j]; vld[j] = (myki[j] <= t); }

    float acc[4][4] = {};
    for (int c0 = 0; c0 < CKV_; c0 += 16) {
        __syncthreads();
        {
            const int u = tid & 3, kr0 = tid >> 2;
            #pragma unroll
            for (int rep = 0; rep < 4; ++rep) {
                int k = kr0 + 64 * rep;
                float4 v = kvkey4[(long)kidxs[k] * 144 + (c0 >> 2) + u];
                KsT[(4*u+0)*260 + k] = v.x;
                KsT[(4*u+1)*260 + k] = v.y;
                KsT[(4*u+2)*260 + k] = v.z;
                KsT[(4*u+3)*260 + k] = v.w;
            }
        }
        __syncthreads();
        #pragma unroll
        for (int cg = 0; cg < 4; ++cg) {
            float qs[4][4];
            #pragma unroll
            for (int i = 0; i < 4; ++i) {
                float4 qv = qk4[(4*hq + i) * 144 + (c0 >> 2) + cg];
                qs[i][0] = qv.x; qs[i][1] = qv.y; qs[i][2] = qv.z; qs[i][3] = qv.w;
            }
            #pragma unroll
            for (int j4 = 0; j4 < 4; ++j4) {
                const float4 ks = *(const float4*)&KsT[(cg*4 + j4)*260 + 4*kq];
                #pragma unroll
                for (int i = 0; i < 4; ++i) {
                    acc[i][0] += qs[i][j4] * ks.x;
                    acc[i][1] += qs[i][j4] * ks.y;
                    acc[i][2] += qs[i][j4] * ks.z;
                    acc[i][3] += qs[i][j4] * ks.w;
                }
            }
        }
    }
    __syncthreads();

    float p[4][4];
    #pragma unroll
    for (int i = 0; i < 4; ++i) {
        float l[4]; float lm = -INFINITY;
        #pragma unroll
        for (int j = 0; j < 4; ++j) {
            l[j] = vld[j] ? acc[i][j] * SCALE_LOG : -INFINITY;
            lm = fmaxf(lm, l[j]);
        }
        for (int off = 32; off; off >>= 1) lm = fmaxf(lm, __shfl_xor(lm, off, 64));
        float s = 0.f;
        #pragma unroll
        for (int j = 0; j < 4; ++j) {
            float e = vld[j] ? expf(l[j] - lm) : 0.f;
            p[i][j] = e; s += e;
        }
        for (int off = 32; off; off >>= 1) s += __shfl_xor(s, off, 64);
        float inv = 1.f / s;
        #pragma unroll
        for (int j = 0; j < 4; ++j) p[i][j] *= inv;
    }
    #pragma unroll
    for (int j = 0; j < 4; ++j)
        #pragma unroll
        for (int i = 0; i < 4; ++i)
            PT[(4*kq + j) * 20 + 4*hq + i] = p[i][j];
    __syncthreads();

    for (int c0 = 0; c0 < KVLR_; c0 += 256) {
        float a2[4][4] = {};
        for (int k0 = 0; k0 < TOPK_; k0 += 32) {
            __syncthreads();
            #pragma unroll
            for (int rep = 0; rep < 8; ++rep) {
                int e = rep * 256 + tid;
                int kk = e >> 6, u = e & 63;
                float4 v = kvkey4[(long)kidxs[k0 + kk] * 144 + (c0 >> 2) + u];
                *(float4*)&Sel[kk * 260 + 4 * u] = v;
            }
            __syncthreads();
            #pragma unroll
            for (int kk = 0; kk < 32; ++kk) {
                const float4 pt = *(const float4*)&PT[(k0 + kk) * 20 + 4 * hq];
                const float4 sv = *(const float4*)&Sel[kk * 260 + 4 * kq];
                const float pf[4] = {pt.x, pt.y, pt.z, pt.w};
                #pragma unroll
                for (int i = 0; i < 4; ++i) {
                    a2[i][0] += pf[i] * sv.x;
                    a2[i][1] += pf[i] * sv.y;
                    a2[i][2] += pf[i] * sv.z;
                    a2[i][3] += pf[i] * sv.w;
                }
            }
        }
        #pragma unroll
        for (int i = 0; i < 4; ++i) {
            float4 o = make_float4(a2[i][0], a2[i][1], a2[i][2], a2[i][3]);
            *(float4*)&olat[((long)t * H_ + 4*hq + i) * 512 + c0 + 4 * kq] = o;
        }
    }
}

// ---------------------------------------------------------------------------
extern "C" void kernel_launch(void* const* d_in, const int* in_sizes, int n_in,
                              void* d_out, int out_size, void* d_ws, size_t ws_size,
                              hipStream_t stream)
{
    const float* x          = (const float*)d_in[0];
    const float* cosb       = (const float*)d_in[1];
    const float* sinb       = (const float*)d_in[2];
    const float* wq_a       = (const float*)d_in[3];
    const float* q_norm_w   = (const float*)d_in[4];
    const float* wq_b       = (const float*)d_in[5];
    const float* wkv_a      = (const float*)d_in[6];
    const float* kv_norm_w  = (const float*)d_in[7];
    const float* wkv_b      = (const float*)d_in[8];
    const float* wo         = (const float*)d_in[9];
    const float* iq_norm_w  = (const float*)d_in[10];
    const float* iwq_b      = (const float*)d_in[11];
    const float* iwk        = (const float*)d_in[12];
    const float* k_norm_w   = (const float*)d_in[13];
    const float* k_norm_b   = (const float*)d_in[14];
    const float* wproj      = (const float*)d_in[15];
    float* out = (float*)d_out;

    // fp32 workspace (float offsets) -- identical footprint to round 2 (~90 MB)
    float* ws    = (float*)d_ws;
    float* qr    = ws;                      // 1,048,576
    float* rstd  = ws + 1048576;            // 1,024
    float* wtok  = ws + 1049600;            // 16,384
    float* kvkey = ws + 1065984;            // 589,824
    int*   topk  = (int*)(ws + 1655808);    // 262,144 ints
    float* qkey  = ws + 1917952;            // 9,437,184
    float* outv  = ws + 11355136;           // 2,097,152
    float* U0    = ws + 13452288;           // union region
    float* iq    = U0;                      // 2,097,152
    float* ik    = U0 + 2097152;            // 2,097,152
    float* kva   = U0 + 4194304;            // 589,824
    float* qbuf  = U0 + 4784128;            // 3,145,728
    float* score = U0 + 7929856;            // 1,048,576
    float* olat  = U0;                      // 8,388,608 (late phase)

    // bf16 sublayouts carved from dead zones (ushort units)
    unsigned short* qkey_u = (unsigned short*)qkey;      // free until qpe/qnope
    unsigned short* wqa_hi  = qkey_u;                    // 2,097,152
    unsigned short* wqa_lo  = qkey_u + 2097152;
    unsigned short* iwk_hi  = qkey_u + 4194304;          // 4,194,304
    unsigned short* iwk_lo  = qkey_u + 8388608;
    unsigned short* iwqb_hi = qkey_u + 12582912;         // 2,097,152
    unsigned short* iwqb_lo = qkey_u + 14680064;
    unsigned short* qriq_hi = qkey_u + 16777216;         // 1,048,576
    unsigned short* qriq_lo = qkey_u + 17825792;
    // late-phase reuse of qkey region (dead after attn2):
    unsigned short* olat_bf = qkey_u;                    // 8,388,608
    unsigned short* wkvb_bf = qkey_u + 8388608;          // 2,097,152
    unsigned short* outv_bf = qkey_u + 10485760;         // 2,097,152
    unsigned short* wo_bf   = qkey_u + 12582912;         // 4,194,304
    // q slot (free until q GEMM writes it):
    unsigned short* q_u     = (unsigned short*)qbuf;
    unsigned short* x_hi    = q_u;                       // 2,097,152
    unsigned short* x_lo    = q_u + 2097152;
    unsigned short* wkva_hi = q_u + 4194304;             // 1,179,648
    // outv slot (free until outv GEMM):
    unsigned short* outv_u  = (unsigned short*)outv;
    unsigned short* wqb_hi  = outv_u;                    // 3,145,728
    unsigned short* qrq_hi  = outv_u + 3145728;          // 1,048,576
    // iq / ik slots (free after score2):
    unsigned short* qbf     = (unsigned short*)iq;       // 3,145,728
    unsigned short* wkT     = (unsigned short*)ik;       // 1,048,576

    #define CAST(src, hi, lo, n, cw, rs, K) \
        cast_hl_k<<<(n)/1024, 256, 0, stream>>>((src), (hi), (lo), (n), (cw), (rs), (K))

    // ---- casts (early) ----
    CAST(x,     x_hi,   x_lo,   2097152L, nullptr, nullptr, 0);
    CAST(wq_a,  wqa_hi, wqa_lo, 2097152L, nullptr, nullptr, 0);
    CAST(iwk,   iwk_hi, iwk_lo, 4194304L, nullptr, nullptr, 0);
    CAST(iwq_b, iwqb_hi,iwqb_lo,2097152L, nullptr, nullptr, 0);
    CAST(wkv_a, wkva_hi,nullptr,1179648L, nullptr, nullptr, 0);
    CAST(wq_b,  wqb_hi, nullptr,3145728L, nullptr, nullptr, 0);

    // ---- qr = x @ wq_a.T (bf16x3) ----
    dim3 gqr(QLR_/128, T_/128, 1);
    gemm_bt_mfma_k<<<gqr, 256, 0, stream>>>(x_hi, wqa_hi, qr, 0,0,0, DIM_, DIM_, QLR_, QLR_, DIM_, 0);
    gemm_bt_mfma_k<<<gqr, 256, 0, stream>>>(x_hi, wqa_lo, qr, 0,0,0, DIM_, DIM_, QLR_, QLR_, DIM_, 1);
    gemm_bt_mfma_k<<<gqr, 256, 0, stream>>>(x_lo, wqa_hi, qr, 0,0,0, DIM_, DIM_, QLR_, QLR_, DIM_, 1);

    rstd_k<<<T_, 256, 0, stream>>>(qr, rstd);
    CAST(qr, qriq_hi, qriq_lo, 1048576L, iq_norm_w, rstd, QLR_);
    CAST(qr, qrq_hi,  nullptr, 1048576L, q_norm_w,  rstd, QLR_);

    // ---- iq = rmsnorm(qr,iq_norm) @ iwq_b.T (bf16x3) ----
    dim3 giq(IH_*ID_/128, T_/128, 1);
    gemm_bt_mfma_k<<<giq, 256, 0, stream>>>(qriq_hi, iwqb_hi, iq, 0,0,0, QLR_, QLR_, IH_*ID_, IH_*ID_, QLR_, 0);
    gemm_bt_mfma_k<<<giq, 256, 0, stream>>>(qriq_hi, iwqb_lo, iq, 0,0,0, QLR_, QLR_, IH_*ID_, IH_*ID_, QLR_, 1);
    gemm_bt_mfma_k<<<giq, 256, 0, stream>>>(qriq_lo, iwqb_hi, iq, 0,0,0, QLR_, QLR_, IH_*ID_, IH_*ID_, QLR_, 1);

    // ---- ik = x @ iwk.T (bf16x3) ----
    dim3 gik(IH_*ID_/128, T_/128, 1);
    gemm_bt_mfma_k<<<gik, 256, 0, stream>>>(x_hi, iwk_hi, ik, 0,0,0, DIM_, DIM_, IH_*ID_, IH_*ID_, DIM_, 0);
    gemm_bt_mfma_k<<<gik, 256, 0, stream>>>(x_hi, iwk_lo, ik, 0,0,0, DIM_, DIM_, IH_*ID_, IH_*ID_, DIM_, 1);
    gemm_bt_mfma_k<<<gik, 256, 0, stream>>>(x_lo, iwk_hi, ik, 0,0,0, DIM_, DIM_, IH_*ID_, IH_*ID_, DIM_, 1);

    // ---- kva = x @ wkv_a.T (bf16, N=576 guarded) ----
    gemm_bt_mfma_k<<<dim3((CKV_+127)/128, T_/128, 1), 256, 0, stream>>>(
        x_hi, wkva_hi, kva, 0,0,0, DIM_, DIM_, CKV_, CKV_, DIM_, 0);

    // ---- q = rmsnorm(qr,q_norm) @ wq_b.T (bf16; overwrites x_hi/x_lo/wkva region) ----
    gemm_bt_mfma_k<<<dim3(H_*QKD_/128, T_/128, 1), 256, 0, stream>>>(
        qrq_hi, wqb_hi, qbuf, 0,0,0, QLR_, QLR_, H_*QKD_, H_*QKD_, QLR_, 0);

    // ---- wtok (fused fp32) ----
    wtok_k<<<T_, 256, 0, stream>>>(x, wproj, wtok);

    // ---- per-row transforms ----
    transform_iq_k<<<T_*IH_, 128, 0, stream>>>(iq, cosb, sinb);
    transform_ik_k<<<T_*IH_, 128, 0, stream>>>(ik, k_norm_w, k_norm_b, cosb, sinb);
    transform_kv_k<<<T_, 256, 0, stream>>>(kva, kvkey, kv_norm_w, cosb, sinb);

    // ---- indexer scores + topk (fp32) ----
    score2_k<<<dim3(T_/64, T_/64), 256, 0, stream>>>(iq, ik, wtok, score);
    topk_k<<<T_, 512, 0, stream>>>(score, topk);

    // ---- q_key assembly (qkey region now free of bf16 casts) ----
    CAST(qbuf, qbf, nullptr, 3145728L, nullptr, nullptr, 0);       // into iq slot
    tcast_k<<<dim3(16, 4, 16), 256, 0, stream>>>(wkv_b, wkT);      // into ik slot
    qpe_k<<<T_*H_/2, 64, 0, stream>>>(qbuf, qkey, cosb, sinb);
    gemm_bt_mfma_k<<<dim3(KVLR_/128, T_/128, H_), 256, 0, stream>>>(
        qbf, wkT, qkey, 192L, 65536L, 576L, H_*QKD_, ID_, H_*CKV_, KVLR_, ID_, 0);

    // ---- attention -> out_latent (overwrites U0 incl. qbf/wkT) ----
    attn2_k<<<T_, 256, 0, stream>>>(qkey, kvkey, topk, olat);

    // ---- out_v = out_latent @ w_v^T (bf16 batched) ----
    CAST(olat, olat_bf, nullptr, 8388608L, nullptr, nullptr, 0);   // qkey region (dead)
    CAST(wkv_b, wkvb_bf, nullptr, 2097152L, nullptr, nullptr, 0);
    gemm_bt_mfma_k<<<dim3(VD_/128, T_/128, H_), 256, 0, stream>>>(
        olat_bf, wkvb_bf + (long)NOPE_*KVLR_, outv,
        512L, (long)(NOPE_+VD_)*KVLR_, (long)VD_,
        H_*KVLR_, KVLR_, H_*VD_, VD_, KVLR_, 0);

    // ---- out = outv @ wo.T (bf16) ----
    CAST(outv, outv_bf, nullptr, 2097152L, nullptr, nullptr, 0);
    CAST(wo,   wo_bf,   nullptr, 4194304L, nullptr, nullptr, 0);
    gemm_bt_mfma_k<<<dim3(DIM_/128, T_/128, 1), 256, 0, stream>>>(
        outv_bf, wo_bf, out, 0,0,0, H_*VD_, H_*VD_, DIM_, DIM_, H_*VD_, 0);

    #undef CAST
    (void)in_sizes; (void)n_in; (void)out_size; (void)ws_size;
}

// Round 4
// 847.831 us; speedup vs baseline: 4.7683x; 1.4498x over previous
//
#include <hip/hip_runtime.h>
#include <hip/hip_bf16.h>
#include <math.h>

// Problem constants
#define T_     1024
#define DIM_   2048
#define H_     16
#define QLR_   1024
#define KVLR_  512
#define NOPE_  128
#define ROPE_  64
#define VD_    128
#define QKD_   192   // NOPE+ROPE
#define IH_    16
#define ID_    128
#define TOPK_  256
#define CKV_   576   // KVLR + ROPE

#define SCALE_W    0.022097086912079608f   // IH^-0.5 * ID^-0.5
#define SCALE_LOG  0.07216878364870323f    // QKD^-0.5

typedef short bfrag __attribute__((ext_vector_type(8)));   // 8 bf16 = 4 VGPRs
typedef float ffrag __attribute__((ext_vector_type(4)));   // 4 fp32 acc

__device__ __forceinline__ unsigned short f2bf(float f) {
    union { __hip_bfloat16 h; unsigned short u; } c; c.h = __float2bfloat16(f); return c.u;
}
__device__ __forceinline__ float bf2f(unsigned short u) {
    union { unsigned short u; __hip_bfloat16 h; } c; c.u = u; return __bfloat162float(c.h);
}

// ---------------------------------------------------------------------------
// fp32 -> bf16 cast, optional hi/lo split and per-row/col scaling.
// ---------------------------------------------------------------------------
__global__ __launch_bounds__(256) void cast_hl_k(
    const float* __restrict__ in, unsigned short* __restrict__ hi,
    unsigned short* __restrict__ lo, long n,
    const float* __restrict__ colw, const float* __restrict__ rowscale, int Kc)
{
    long base = ((long)blockIdx.x * 256 + threadIdx.x) * 4;
    if (base >= n) return;
    float4 v = *(const float4*)(in + base);
    float s[4] = {v.x, v.y, v.z, v.w};
    if (colw) {
        int col = (int)(base % Kc);
        float4 cw = *(const float4*)(colw + col);
        s[0] *= cw.x; s[1] *= cw.y; s[2] *= cw.z; s[3] *= cw.w;
    }
    if (rowscale) {
        float r = rowscale[base / Kc];
        s[0] *= r; s[1] *= r; s[2] *= r; s[3] *= r;
    }
    ushort4 h4;
    h4.x = f2bf(s[0]); h4.y = f2bf(s[1]); h4.z = f2bf(s[2]); h4.w = f2bf(s[3]);
    *(ushort4*)(hi + base) = h4;
    if (lo) {
        ushort4 l4;
        l4.x = f2bf(s[0] - bf2f(h4.x));
        l4.y = f2bf(s[1] - bf2f(h4.y));
        l4.z = f2bf(s[2] - bf2f(h4.z));
        l4.w = f2bf(s[3] - bf2f(h4.w));
        *(ushort4*)(lo + base) = l4;
    }
}

// ---------------------------------------------------------------------------
// Transpose-cast w_k: wkT[h][c][d] = bf16(wkv_b[(h*256+d)*512 + c]), d<128, c<512
// ---------------------------------------------------------------------------
__global__ __launch_bounds__(256) void tcast_k(const float* __restrict__ in,
                                               unsigned short* __restrict__ out)
{
    int h = blockIdx.z, c0 = blockIdx.x * 32, d0 = blockIdx.y * 32;
    __shared__ float t[32][33];
    int tx = threadIdx.x & 31, ty = threadIdx.x >> 5;
    #pragma unroll
    for (int i = 0; i < 4; ++i)
        t[ty + i * 8][tx] = in[(long)(h * 256 + d0 + ty + i * 8) * 512 + c0 + tx];
    __syncthreads();
    #pragma unroll
    for (int i = 0; i < 4; ++i)
        out[((long)h * 512 + c0 + ty + i * 8) * 128 + d0 + tx] = f2bf(t[tx][ty + i * 8]);
}

// ---------------------------------------------------------------------------
// MFMA bf16 NT GEMM, 128x128 tile (kept for batched q_nope_proj).
// ---------------------------------------------------------------------------
__global__ __launch_bounds__(256) void gemm_bt_mfma_k(
    const unsigned short* __restrict__ A, const unsigned short* __restrict__ B,
    float* __restrict__ C, long sA, long sB, long sC,
    int lda, int ldb, int ldc, int N, int K, int beta)
{
    A += (long)blockIdx.z * sA;
    B += (long)blockIdx.z * sB;
    C += (long)blockIdx.z * sC;
    __shared__ unsigned short As[128 * 40];
    __shared__ unsigned short Bs[128 * 40];
    const int tid = threadIdx.x;
    const int bm = blockIdx.y * 128, bn = blockIdx.x * 128;
    const int wave = tid >> 6, lane = tid & 63;
    const int wm = (wave >> 1) * 64, wn = (wave & 1) * 64;
    const int lm = lane & 15, quad = lane >> 4;

    ffrag acc[4][4];
    if (beta) {
        #pragma unroll
        for (int mi = 0; mi < 4; ++mi)
            #pragma unroll
            for (int ni = 0; ni < 4; ++ni) {
                int n = bn + wn + ni * 16 + lm;
                int mb = bm + wm + mi * 16 + quad * 4;
                #pragma unroll
                for (int r = 0; r < 4; ++r)
                    acc[mi][ni][r] = (n < N) ? C[(long)(mb + r) * ldc + n] : 0.f;
            }
    } else {
        #pragma unroll
        for (int mi = 0; mi < 4; ++mi)
            #pragma unroll
            for (int ni = 0; ni < 4; ++ni)
                #pragma unroll
                for (int r = 0; r < 4; ++r) acc[mi][ni][r] = 0.f;
    }

    const int srow = tid >> 1, shalf = tid & 1;
    const long aoff = (long)(bm + srow) * lda + shalf * 16;
    int brow = bn + srow; if (brow > N - 1) brow = N - 1;
    const long boff = (long)brow * ldb + shalf * 16;
    unsigned short* la = As + srow * 40 + shalf * 16;
    unsigned short* lb = Bs + srow * 40 + shalf * 16;

    for (int k0 = 0; k0 < K; k0 += 32) {
        __syncthreads();
        uint4 va0 = *(const uint4*)(A + aoff + k0);
        uint4 va1 = *(const uint4*)(A + aoff + k0 + 8);
        uint4 vb0 = *(const uint4*)(B + boff + k0);
        uint4 vb1 = *(const uint4*)(B + boff + k0 + 8);
        *(uint4*)la = va0; *(uint4*)(la + 8) = va1;
        *(uint4*)lb = vb0; *(uint4*)(lb + 8) = vb1;
        __syncthreads();
        bfrag af[4], bf[4];
        #pragma unroll
        for (int mi = 0; mi < 4; ++mi)
            af[mi] = *(const bfrag*)(As + (wm + mi * 16 + lm) * 40 + quad * 8);
        #pragma unroll
        for (int ni = 0; ni < 4; ++ni)
            bf[ni] = *(const bfrag*)(Bs + (wn + ni * 16 + lm) * 40 + quad * 8);
        #pragma unroll
        for (int mi = 0; mi < 4; ++mi)
            #pragma unroll
            for (int ni = 0; ni < 4; ++ni)
                acc[mi][ni] = __builtin_amdgcn_mfma_f32_16x16x32_bf16(
                    af[mi], bf[ni], acc[mi][ni], 0, 0, 0);
    }

    #pragma unroll
    for (int mi = 0; mi < 4; ++mi)
        #pragma unroll
        for (int ni = 0; ni < 4; ++ni) {
            int n = bn + wn + ni * 16 + lm;
            if (n < N) {
                int mb = bm + wm + mi * 16 + quad * 4;
                #pragma unroll
                for (int r = 0; r < 4; ++r)
                    C[(long)(mb + r) * ldc + n] = acc[mi][ni][r];
            }
        }
}

// ---------------------------------------------------------------------------
// MFMA bf16 NT GEMM, 64x64 tile (4 waves x 32x32) -- high block count for
// the small shapes in this pipeline. M%64==0; N guarded; K%32==0. Batched.
// ---------------------------------------------------------------------------
__global__ __launch_bounds__(256) void gemm_bt64_k(
    const unsigned short* __restrict__ A, const unsigned short* __restrict__ B,
    float* __restrict__ C, long sA, long sB, long sC,
    int lda, int ldb, int ldc, int N, int K, int beta)
{
    A += (long)blockIdx.z * sA;
    B += (long)blockIdx.z * sB;
    C += (long)blockIdx.z * sC;
    __shared__ unsigned short As[64 * 40];
    __shared__ unsigned short Bs[64 * 40];
    const int tid = threadIdx.x;
    const int bm = blockIdx.y * 64, bn = blockIdx.x * 64;
    const int wave = tid >> 6, lane = tid & 63;
    const int wm = (wave >> 1) * 32, wn = (wave & 1) * 32;
    const int lm = lane & 15, quad = lane >> 4;

    ffrag acc[2][2];
    if (beta) {
        #pragma unroll
        for (int mi = 0; mi < 2; ++mi)
            #pragma unroll
            for (int ni = 0; ni < 2; ++ni) {
                int n = bn + wn + ni * 16 + lm;
                int mb = bm + wm + mi * 16 + quad * 4;
                #pragma unroll
                for (int r = 0; r < 4; ++r)
                    acc[mi][ni][r] = (n < N) ? C[(long)(mb + r) * ldc + n] : 0.f;
            }
    } else {
        #pragma unroll
        for (int mi = 0; mi < 2; ++mi)
            #pragma unroll
            for (int ni = 0; ni < 2; ++ni)
                #pragma unroll
                for (int r = 0; r < 4; ++r) acc[mi][ni][r] = 0.f;
    }

    const int srow = tid >> 2, schunk = tid & 3;
    const long aoff = (long)(bm + srow) * lda + schunk * 8;
    int brow = bn + srow; if (brow > N - 1) brow = N - 1;
    const long boff = (long)brow * ldb + schunk * 8;
    unsigned short* la = As + srow * 40 + schunk * 8;
    unsigned short* lb = Bs + srow * 40 + schunk * 8;

    for (int k0 = 0; k0 < K; k0 += 32) {
        __syncthreads();
        uint4 va = *(const uint4*)(A + aoff + k0);
        uint4 vb = *(const uint4*)(B + boff + k0);
        *(uint4*)la = va;
        *(uint4*)lb = vb;
        __syncthreads();
        bfrag af[2], bf[2];
        #pragma unroll
        for (int mi = 0; mi < 2; ++mi)
            af[mi] = *(const bfrag*)(As + (wm + mi * 16 + lm) * 40 + quad * 8);
        #pragma unroll
        for (int ni = 0; ni < 2; ++ni)
            bf[ni] = *(const bfrag*)(Bs + (wn + ni * 16 + lm) * 40 + quad * 8);
        #pragma unroll
        for (int mi = 0; mi < 2; ++mi)
            #pragma unroll
            for (int ni = 0; ni < 2; ++ni)
                acc[mi][ni] = __builtin_amdgcn_mfma_f32_16x16x32_bf16(
                    af[mi], bf[ni], acc[mi][ni], 0, 0, 0);
    }

    #pragma unroll
    for (int mi = 0; mi < 2; ++mi)
        #pragma unroll
        for (int ni = 0; ni < 2; ++ni) {
            int n = bn + wn + ni * 16 + lm;
            if (n < N) {
                int mb = bm + wm + mi * 16 + quad * 4;
                #pragma unroll
                for (int r = 0; r < 4; ++r)
                    C[(long)(mb + r) * ldc + n] = acc[mi][ni][r];
            }
        }
}

// ---------------------------------------------------------------------------
// Fused wtok: wtok[t,h] = dot(x[t,:], wproj[h,:]) * SCALE_W  (fp32)
// ---------------------------------------------------------------------------
__global__ __launch_bounds__(256) void wtok_k(const float* __restrict__ x,
    const float* __restrict__ wproj, float* __restrict__ wtok)
{
    int t = blockIdx.x, tid = threadIdx.x;
    __shared__ float xs[DIM_];
    for (int c = tid; c < DIM_; c += 256) xs[c] = x[(long)t * DIM_ + c];
    __syncthreads();
    int wave = tid >> 6, lane = tid & 63;
    #pragma unroll
    for (int i = 0; i < 4; ++i) {
        int h = wave * 4 + i;
        float s = 0.f;
        for (int c = lane; c < DIM_; c += 64) s += xs[c] * wproj[(long)h * DIM_ + c];
        for (int off = 32; off; off >>= 1) s += __shfl_xor(s, off, 64);
        if (lane == 0) wtok[(long)t * IH_ + h] = s * SCALE_W;
    }
}

// ---------------------------------------------------------------------------
__global__ __launch_bounds__(256) void rstd_k(const float* __restrict__ qr, float* __restrict__ rstd)
{
    int t = blockIdx.x, tid = threadIdx.x;
    float s = 0.f;
    for (int c = tid; c < QLR_; c += 256) { float v = qr[(long)t * QLR_ + c]; s += v * v; }
    __shared__ float red[256];
    red[tid] = s; __syncthreads();
    for (int off = 128; off; off >>= 1) { if (tid < off) red[tid] += red[tid + off]; __syncthreads(); }
    if (tid == 0) rstd[t] = rsqrtf(red[0] / (float)QLR_ + 1e-6f);
}

// ---------------------------------------------------------------------------
__device__ __forceinline__ void rope_rotate_128(float* s, float* w2, int tid, int t,
    const float* __restrict__ cosb, const float* __restrict__ sinb)
{
    float n1 = 0.f, n2 = 0.f;
    if (tid < 32) {
        float x1 = s[tid], x2 = s[tid + 32];
        float c = cosb[t * 32 + tid], sn = sinb[t * 32 + tid];
        n1 = x1 * c - x2 * sn;
        n2 = x1 * sn + x2 * c;
    }
    __syncthreads();
    if (tid < 32) { s[tid] = n1; s[tid + 32] = n2; }
    __syncthreads();
    const int g = tid >> 6, p = tid & 63;
    w2[tid] = s[((1 - g) << 6) + p];
    __syncthreads();
    #pragma unroll
    for (int h = 1; h < 64; h <<= 1) {
        float a = w2[tid], b = w2[(g << 6) + (p ^ h)];
        __syncthreads();
        w2[tid] = (p & h) ? (b - a) : (a + b);
        __syncthreads();
    }
}

__global__ __launch_bounds__(128) void transform_iq_k(float* __restrict__ iq,
    const float* __restrict__ cosb, const float* __restrict__ sinb)
{
    int row = blockIdx.x;
    int t = row / IH_;
    int tid = threadIdx.x;
    __shared__ float s[128], w2[128];
    s[tid] = iq[(long)row * 128 + tid];
    __syncthreads();
    rope_rotate_128(s, w2, tid, t, cosb, sinb);
    iq[(long)row * 128 + tid] = w2[tid];
}

__global__ __launch_bounds__(128) void transform_ik_k(float* __restrict__ ik,
    const float* __restrict__ knw, const float* __restrict__ knb,
    const float* __restrict__ cosb, const float* __restrict__ sinb)
{
    int row = blockIdx.x;
    int t = row / IH_;
    int tid = threadIdx.x;
    __shared__ float s[128], w2[128], red[128];
    float v = ik[(long)row * 128 + tid];
    red[tid] = v; __syncthreads();
    for (int off = 64; off; off >>= 1) { if (tid < off) red[tid] += red[tid + off]; __syncthreads(); }
    float m = red[0] / 128.f; __syncthreads();
    float d = v - m;
    red[tid] = d * d; __syncthreads();
    for (int off = 64; off; off >>= 1) { if (tid < off) red[tid] += red[tid + off]; __syncthreads(); }
    float var = red[0] / 128.f;
    s[tid] = d * rsqrtf(var + 1e-5f) * knw[tid] + knb[tid];
    __syncthreads();
    rope_rotate_128(s, w2, tid, t, cosb, sinb);
    ik[(long)row * 128 + tid] = w2[tid];
}

__global__ __launch_bounds__(256) void transform_kv_k(const float* __restrict__ kva,
    float* __restrict__ kvkey, const float* __restrict__ kvnw,
    const float* __restrict__ cosb, const float* __restrict__ sinb)
{
    int t = blockIdx.x, tid = threadIdx.x;
    const float* a = kva + (long)t * CKV_;
    float* o = kvkey + (long)t * CKV_;
    float v0 = a[tid], v1 = a[tid + 256];
    __shared__ float red[256];
    __shared__ float rsh;
    red[tid] = v0 * v0 + v1 * v1; __syncthreads();
    for (int off = 128; off; off >>= 1) { if (tid < off) red[tid] += red[tid + off]; __syncthreads(); }
    if (tid == 0) rsh = rsqrtf(red[0] / (float)KVLR_ + 1e-6f);
    __syncthreads();
    float rs = rsh;
    o[tid]       = v0 * rs * kvnw[tid];
    o[tid + 256] = v1 * rs * kvnw[tid + 256];
    if (tid < 32) {
        float x1 = a[512 + tid], x2 = a[544 + tid];
        float c = cosb[t * 32 + tid], sn = sinb[t * 32 + tid];
        o[512 + tid] = x1 * c - x2 * sn;
        o[544 + tid] = x1 * sn + x2 * c;
    }
}

__global__ __launch_bounds__(64) void qpe_k(const float* __restrict__ q, float* __restrict__ qkey,
    const float* __restrict__ cosb, const float* __restrict__ sinb)
{
    int row = blockIdx.x * 2 + (threadIdx.x >> 5);
    int i = threadIdx.x & 31;
    int t = row / H_;
    const float* qp = q + (long)row * QKD_ + NOPE_;
    float x1 = qp[i], x2 = qp[i + 32];
    float c = cosb[t * 32 + i], sn = sinb[t * 32 + i];
    float* o = qkey + (long)row * CKV_ + 512;
    o[i]      = x1 * c - x2 * sn;
    o[i + 32] = x1 * sn + x2 * c;
}

// ---------------------------------------------------------------------------
// Indexer score v3 (MFMA bf16x3): 64x64 tile per block, 4 waves x 32x32,
// per-head relu + weight, 3-pass hi/lo split for fp32-class accuracy.
// iq/ik bf16 layout: [t][h*128+d] rows of 2048.
// ---------------------------------------------------------------------------
__global__ __launch_bounds__(256) void score3_k(
    const unsigned short* __restrict__ iqh, const unsigned short* __restrict__ iql,
    const unsigned short* __restrict__ ikh, const unsigned short* __restrict__ ikl,
    const float* __restrict__ wtok, float* __restrict__ score)
{
    const int bt = blockIdx.y, bs = blockIdx.x;
    if (bs > bt) return;
    __shared__ unsigned short Ah[64 * 40], Al[64 * 40], Bh[64 * 40], Bl[64 * 40];
    __shared__ float wts[64][16];
    const int tid = threadIdx.x;
    const int wave = tid >> 6, lane = tid & 63;
    const int wm = (wave >> 1) * 32, wn = (wave & 1) * 32;
    const int lm = lane & 15, quad = lane >> 4;
    const int t0 = bt * 64, s0 = bs * 64;
    const int srow = tid >> 2, schunk = tid & 3;

    for (int e = tid; e < 1024; e += 256)
        wts[e >> 4][e & 15] = wtok[(long)(t0 + (e >> 4)) * IH_ + (e & 15)];

    float accf[2][2][4] = {};

    for (int h = 0; h < IH_; ++h) {
        ffrag acch[2][2];
        #pragma unroll
        for (int mi = 0; mi < 2; ++mi)
            #pragma unroll
            for (int ni = 0; ni < 2; ++ni)
                #pragma unroll
                for (int r = 0; r < 4; ++r) acch[mi][ni][r] = 0.f;

        #pragma unroll
        for (int k0 = 0; k0 < ID_; k0 += 32) {
            __syncthreads();
            const long ao = (long)(t0 + srow) * 2048 + h * 128 + k0 + schunk * 8;
            const long bo = (long)(s0 + srow) * 2048 + h * 128 + k0 + schunk * 8;
            *(uint4*)(Ah + srow * 40 + schunk * 8) = *(const uint4*)(iqh + ao);
            *(uint4*)(Al + srow * 40 + schunk * 8) = *(const uint4*)(iql + ao);
            *(uint4*)(Bh + srow * 40 + schunk * 8) = *(const uint4*)(ikh + bo);
            *(uint4*)(Bl + srow * 40 + schunk * 8) = *(const uint4*)(ikl + bo);
            __syncthreads();
            bfrag ah[2], alo[2], bh[2], blo[2];
            #pragma unroll
            for (int mi = 0; mi < 2; ++mi) {
                ah[mi]  = *(const bfrag*)(Ah + (wm + mi * 16 + lm) * 40 + quad * 8);
                alo[mi] = *(const bfrag*)(Al + (wm + mi * 16 + lm) * 40 + quad * 8);
            }
            #pragma unroll
            for (int ni = 0; ni < 2; ++ni) {
                bh[ni]  = *(const bfrag*)(Bh + (wn + ni * 16 + lm) * 40 + quad * 8);
                blo[ni] = *(const bfrag*)(Bl + (wn + ni * 16 + lm) * 40 + quad * 8);
            }
            #pragma unroll
            for (int mi = 0; mi < 2; ++mi)
                #pragma unroll
                for (int ni = 0; ni < 2; ++ni) {
                    acch[mi][ni] = __builtin_amdgcn_mfma_f32_16x16x32_bf16(ah[mi],  bh[ni],  acch[mi][ni], 0, 0, 0);
                    acch[mi][ni] = __builtin_amdgcn_mfma_f32_16x16x32_bf16(ah[mi],  blo[ni], acch[mi][ni], 0, 0, 0);
                    acch[mi][ni] = __builtin_amdgcn_mfma_f32_16x16x32_bf16(alo[mi], bh[ni],  acch[mi][ni], 0, 0, 0);
                }
        }
        #pragma unroll
        for (int mi = 0; mi < 2; ++mi) {
            float wr[4];
            #pragma unroll
            for (int r = 0; r < 4; ++r) wr[r] = wts[wm + mi * 16 + quad * 4 + r][h];
            #pragma unroll
            for (int ni = 0; ni < 2; ++ni)
                #pragma unroll
                for (int r = 0; r < 4; ++r)
                    accf[mi][ni][r] += fmaxf(acch[mi][ni][r], 0.f) * wr[r];
        }
    }
    #pragma unroll
    for (int mi = 0; mi < 2; ++mi)
        #pragma unroll
        for (int ni = 0; ni < 2; ++ni) {
            int s = s0 + wn + ni * 16 + lm;
            int tb = t0 + wm + mi * 16 + quad * 4;
            #pragma unroll
            for (int r = 0; r < 4; ++r)
                score[(long)(tb + r) * T_ + s] = accf[mi][ni][r];
        }
}

// ---------------------------------------------------------------------------
// Top-256 per row via bitonic sort (ties -> lower index, matches jax top_k)
// ---------------------------------------------------------------------------
__global__ __launch_bounds__(512) void topk_k(const float* __restrict__ score, int* __restrict__ topk)
{
    int t = blockIdx.x, tid = threadIdx.x;
    __shared__ float v[1024];
    __shared__ int ix[1024];
    for (int i = tid; i < 1024; i += 512) {
        v[i] = (i <= t) ? score[(long)t * T_ + i] : -INFINITY;
        ix[i] = i;
    }
    __syncthreads();
    for (int k = 2; k <= 1024; k <<= 1) {
        for (int j = k >> 1; j > 0; j >>= 1) {
            for (int i = tid; i < 1024; i += 512) {
                int l = i ^ j;
                if (l > i) {
                    bool up = ((i & k) == 0);
                    float vi = v[i], vl = v[l];
                    int xi = ix[i], xl = ix[l];
                    bool iBetter = (vi > vl) || (vi == vl && xi < xl);
                    bool doSwap = up ? !iBetter : iBetter;
                    if (doSwap) { v[i] = vl; v[l] = vi; ix[i] = xl; ix[l] = xi; }
                }
            }
            __syncthreads();
        }
    }
    if (tid < 256) topk[(long)t * TOPK_ + tid] = ix[tid];
}

// ---------------------------------------------------------------------------
// Attention: one block per token t, all 16 heads (fp32)
// ---------------------------------------------------------------------------
__global__ __launch_bounds__(256) void attn2_k(
    const float* __restrict__ qkey, const float* __restrict__ kvkey,
    const int* __restrict__ topkp, float* __restrict__ olat)
{
    __shared__ float U[13440];
    __shared__ int kidxs[256];
    const int t = blockIdx.x, tid = threadIdx.x;
    const int hq = tid >> 6, kq = tid & 63;

    float4* qk4 = (float4*)U;
    float*  KsT = U + 9216;
    float*  PT  = U;
    float*  Sel = U + 5120;
    const float4* qkey4  = (const float4*)qkey;
    const float4* kvkey4 = (const float4*)kvkey;

    kidxs[tid] = topkp[(long)t * TOPK_ + tid];
    for (int e = tid; e < 2304; e += 256)
        qk4[e] = qkey4[(long)t * 2304 + e];
    __syncthreads();

    int  myki[4]; bool vld[4];
    #pragma unroll
    for (int j = 0; j < 4; ++j) { myki[j] = kidxs[kq * 4 + j]; vld[j] = (myki[j] <= t); }

    float acc[4][4] = {};
    for (int c0 = 0; c0 < CKV_; c0 += 16) {
        __syncthreads();
        {
            const int u = tid & 3, kr0 = tid >> 2;
            #pragma unroll
            for (int rep = 0; rep < 4; ++rep) {
                int k = kr0 + 64 * rep;
                float4 v = kvkey4[(long)kidxs[k] * 144 + (c0 >> 2) + u];
                KsT[(4*u+0)*260 + k] = v.x;
                KsT[(4*u+1)*260 + k] = v.y;
                KsT[(4*u+2)*260 + k] = v.z;
                KsT[(4*u+3)*260 + k] = v.w;
            }
        }
        __syncthreads();
        #pragma unroll
        for (int cg = 0; cg < 4; ++cg) {
            float qs[4][4];
            #pragma unroll
            for (int i = 0; i < 4; ++i) {
                float4 qv = qk4[(4*hq + i) * 144 + (c0 >> 2) + cg];
                qs[i][0] = qv.x; qs[i][1] = qv.y; qs[i][2] = qv.z; qs[i][3] = qv.w;
            }
            #pragma unroll
            for (int j4 = 0; j4 < 4; ++j4) {
                const float4 ks = *(const float4*)&KsT[(cg*4 + j4)*260 + 4*kq];
                #pragma unroll
                for (int i = 0; i < 4; ++i) {
                    acc[i][0] += qs[i][j4] * ks.x;
                    acc[i][1] += qs[i][j4] * ks.y;
                    acc[i][2] += qs[i][j4] * ks.z;
                    acc[i][3] += qs[i][j4] * ks.w;
                }
            }
        }
    }
    __syncthreads();

    float p[4][4];
    #pragma unroll
    for (int i = 0; i < 4; ++i) {
        float l[4]; float lm = -INFINITY;
        #pragma unroll
        for (int j = 0; j < 4; ++j) {
            l[j] = vld[j] ? acc[i][j] * SCALE_LOG : -INFINITY;
            lm = fmaxf(lm, l[j]);
        }
        for (int off = 32; off; off >>= 1) lm = fmaxf(lm, __shfl_xor(lm, off, 64));
        float s = 0.f;
        #pragma unroll
        for (int j = 0; j < 4; ++j) {
            float e = vld[j] ? expf(l[j] - lm) : 0.f;
            p[i][j] = e; s += e;
        }
        for (int off = 32; off; off >>= 1) s += __shfl_xor(s, off, 64);
        float inv = 1.f / s;
        #pragma unroll
        for (int j = 0; j < 4; ++j) p[i][j] *= inv;
    }
    #pragma unroll
    for (int j = 0; j < 4; ++j)
        #pragma unroll
        for (int i = 0; i < 4; ++i)
            PT[(4*kq + j) * 20 + 4*hq + i] = p[i][j];
    __syncthreads();

    for (int c0 = 0; c0 < KVLR_; c0 += 256) {
        float a2[4][4] = {};
        for (int k0 = 0; k0 < TOPK_; k0 += 32) {
            __syncthreads();
            #pragma unroll
            for (int rep = 0; rep < 8; ++rep) {
                int e = rep * 256 + tid;
                int kk = e >> 6, u = e & 63;
                float4 v = kvkey4[(long)kidxs[k0 + kk] * 144 + (c0 >> 2) + u];
                *(float4*)&Sel[kk * 260 + 4 * u] = v;
            }
            __syncthreads();
            #pragma unroll
            for (int kk = 0; kk < 32; ++kk) {
                const float4 pt = *(const float4*)&PT[(k0 + kk) * 20 + 4 * hq];
                const float4 sv = *(const float4*)&Sel[kk * 260 + 4 * kq];
                const float pf[4] = {pt.x, pt.y, pt.z, pt.w};
                #pragma unroll
                for (int i = 0; i < 4; ++i) {
                    a2[i][0] += pf[i] * sv.x;
                    a2[i][1] += pf[i] * sv.y;
                    a2[i][2] += pf[i] * sv.z;
                    a2[i][3] += pf[i] * sv.w;
                }
            }
        }
        #pragma unroll
        for (int i = 0; i < 4; ++i) {
            float4 o = make_float4(a2[i][0], a2[i][1], a2[i][2], a2[i][3]);
            *(float4*)&olat[((long)t * H_ + 4*hq + i) * 512 + c0 + 4 * kq] = o;
        }
    }
}

// ---------------------------------------------------------------------------
extern "C" void kernel_launch(void* const* d_in, const int* in_sizes, int n_in,
                              void* d_out, int out_size, void* d_ws, size_t ws_size,
                              hipStream_t stream)
{
    const float* x          = (const float*)d_in[0];
    const float* cosb       = (const float*)d_in[1];
    const float* sinb       = (const float*)d_in[2];
    const float* wq_a       = (const float*)d_in[3];
    const float* q_norm_w   = (const float*)d_in[4];
    const float* wq_b       = (const float*)d_in[5];
    const float* wkv_a      = (const float*)d_in[6];
    const float* kv_norm_w  = (const float*)d_in[7];
    const float* wkv_b      = (const float*)d_in[8];
    const float* wo         = (const float*)d_in[9];
    const float* iq_norm_w  = (const float*)d_in[10];
    const float* iwq_b      = (const float*)d_in[11];
    const float* iwk        = (const float*)d_in[12];
    const float* k_norm_w   = (const float*)d_in[13];
    const float* k_norm_b   = (const float*)d_in[14];
    const float* wproj      = (const float*)d_in[15];
    float* out = (float*)d_out;

    // fp32 workspace (float offsets)
    float* ws    = (float*)d_ws;
    float* qr    = ws;                      // 1,048,576
    float* rstd  = ws + 1048576;            // 1,024
    float* wtok  = ws + 1049600;            // 16,384
    float* kvkey = ws + 1065984;            // 589,824
    int*   topk  = (int*)(ws + 1655808);    // 262,144 ints
    float* qkey  = ws + 1917952;            // 9,437,184
    float* outv  = ws + 11355136;           // 2,097,152
    float* U0    = ws + 13452288;           // union region
    float* iq    = U0;                      // 2,097,152
    float* ik    = U0 + 2097152;            // 2,097,152
    float* kva   = U0 + 4194304;            // 589,824
    float* qbuf  = U0 + 4784128;            // 3,145,728
    float* score = U0 + 7929856;            // 1,048,576
    float* olat  = U0;                      // 8,388,608 (late phase)

    // bf16 sublayouts carved from dead zones (ushort units)
    unsigned short* qkey_u = (unsigned short*)qkey;      // free until qpe/qnope
    unsigned short* wqa_hi  = qkey_u;                    // 2,097,152
    unsigned short* wqa_lo  = qkey_u + 2097152;
    unsigned short* iwk_hi  = qkey_u + 4194304;          // 4,194,304
    unsigned short* iwk_lo  = qkey_u + 8388608;
    unsigned short* iwqb_hi = qkey_u + 12582912;         // 2,097,152
    unsigned short* iwqb_lo = qkey_u + 14680064;
    unsigned short* qriq_hi = qkey_u + 16777216;         // 1,048,576
    unsigned short* qriq_lo = qkey_u + 17825792;
    // mid-phase reuse (after qr/iq/ik GEMMs, before qpe): score bf16 inputs
    unsigned short* iqbf_hi = qkey_u;                    // 2,097,152
    unsigned short* iqbf_lo = qkey_u + 2097152;
    unsigned short* ikbf_hi = qkey_u + 4194304;
    unsigned short* ikbf_lo = qkey_u + 6291456;
    // late-phase reuse of qkey region (dead after attn2):
    unsigned short* olat_bf = qkey_u;                    // 8,388,608
    unsigned short* wkvb_bf = qkey_u + 8388608;          // 2,097,152
    unsigned short* outv_bf = qkey_u + 10485760;         // 2,097,152
    unsigned short* wo_bf   = qkey_u + 12582912;         // 4,194,304
    // q slot (free until q GEMM writes it):
    unsigned short* q_u     = (unsigned short*)qbuf;
    unsigned short* x_hi    = q_u;                       // 2,097,152
    unsigned short* x_lo    = q_u + 2097152;
    unsigned short* wkva_hi = q_u + 4194304;             // 1,179,648
    // outv slot (free until outv GEMM):
    unsigned short* outv_u  = (unsigned short*)outv;
    unsigned short* wqb_hi  = outv_u;                    // 3,145,728
    unsigned short* qrq_hi  = outv_u + 3145728;          // 1,048,576
    // iq / ik slots (free after score3):
    unsigned short* qbf     = (unsigned short*)iq;       // 3,145,728
    unsigned short* wkT     = (unsigned short*)ik;       // 1,048,576

    #define CAST(src, hi, lo, n, cw, rs, K) \
        cast_hl_k<<<(n)/1024, 256, 0, stream>>>((src), (hi), (lo), (n), (cw), (rs), (K))

    // ---- casts (early) ----
    CAST(x,     x_hi,   x_lo,   2097152L, nullptr, nullptr, 0);
    CAST(wq_a,  wqa_hi, wqa_lo, 2097152L, nullptr, nullptr, 0);
    CAST(iwk,   iwk_hi, iwk_lo, 4194304L, nullptr, nullptr, 0);
    CAST(iwq_b, iwqb_hi,iwqb_lo,2097152L, nullptr, nullptr, 0);
    CAST(wkv_a, wkva_hi,nullptr,1179648L, nullptr, nullptr, 0);
    CAST(wq_b,  wqb_hi, nullptr,3145728L, nullptr, nullptr, 0);

    // ---- qr = x @ wq_a.T (bf16x3, 64-tile: 256 blocks) ----
    dim3 gqr(QLR_/64, T_/64, 1);
    gemm_bt64_k<<<gqr, 256, 0, stream>>>(x_hi, wqa_hi, qr, 0,0,0, DIM_, DIM_, QLR_, QLR_, DIM_, 0);
    gemm_bt64_k<<<gqr, 256, 0, stream>>>(x_hi, wqa_lo, qr, 0,0,0, DIM_, DIM_, QLR_, QLR_, DIM_, 1);
    gemm_bt64_k<<<gqr, 256, 0, stream>>>(x_lo, wqa_hi, qr, 0,0,0, DIM_, DIM_, QLR_, QLR_, DIM_, 1);

    rstd_k<<<T_, 256, 0, stream>>>(qr, rstd);
    CAST(qr, qriq_hi, qriq_lo, 1048576L, iq_norm_w, rstd, QLR_);
    CAST(qr, qrq_hi,  nullptr, 1048576L, q_norm_w,  rstd, QLR_);

    // ---- iq = rmsnorm(qr,iq_norm) @ iwq_b.T (bf16x3, 512 blocks) ----
    dim3 giq(IH_*ID_/64, T_/64, 1);
    gemm_bt64_k<<<giq, 256, 0, stream>>>(qriq_hi, iwqb_hi, iq, 0,0,0, QLR_, QLR_, IH_*ID_, IH_*ID_, QLR_, 0);
    gemm_bt64_k<<<giq, 256, 0, stream>>>(qriq_hi, iwqb_lo, iq, 0,0,0, QLR_, QLR_, IH_*ID_, IH_*ID_, QLR_, 1);
    gemm_bt64_k<<<giq, 256, 0, stream>>>(qriq_lo, iwqb_hi, iq, 0,0,0, QLR_, QLR_, IH_*ID_, IH_*ID_, QLR_, 1);

    // ---- ik = x @ iwk.T (bf16x3) ----
    gemm_bt64_k<<<giq, 256, 0, stream>>>(x_hi, iwk_hi, ik, 0,0,0, DIM_, DIM_, IH_*ID_, IH_*ID_, DIM_, 0);
    gemm_bt64_k<<<giq, 256, 0, stream>>>(x_hi, iwk_lo, ik, 0,0,0, DIM_, DIM_, IH_*ID_, IH_*ID_, DIM_, 1);
    gemm_bt64_k<<<giq, 256, 0, stream>>>(x_lo, iwk_hi, ik, 0,0,0, DIM_, DIM_, IH_*ID_, IH_*ID_, DIM_, 1);

    // ---- kva = x @ wkv_a.T (bf16, N=576 guarded) ----
    gemm_bt64_k<<<dim3((CKV_+63)/64, T_/64, 1), 256, 0, stream>>>(
        x_hi, wkva_hi, kva, 0,0,0, DIM_, DIM_, CKV_, CKV_, DIM_, 0);

    // ---- q = rmsnorm(qr,q_norm) @ wq_b.T (bf16) ----
    gemm_bt64_k<<<dim3(H_*QKD_/64, T_/64, 1), 256, 0, stream>>>(
        qrq_hi, wqb_hi, qbuf, 0,0,0, QLR_, QLR_, H_*QKD_, H_*QKD_, QLR_, 0);

    // ---- wtok (fused fp32) ----
    wtok_k<<<T_, 256, 0, stream>>>(x, wproj, wtok);

    // ---- per-row transforms ----
    transform_iq_k<<<T_*IH_, 128, 0, stream>>>(iq, cosb, sinb);
    transform_ik_k<<<T_*IH_, 128, 0, stream>>>(ik, k_norm_w, k_norm_b, cosb, sinb);
    transform_kv_k<<<T_, 256, 0, stream>>>(kva, kvkey, kv_norm_w, cosb, sinb);

    // ---- score bf16 hi/lo casts (into dead early-cast region) ----
    CAST(iq, iqbf_hi, iqbf_lo, 2097152L, nullptr, nullptr, 0);
    CAST(ik, ikbf_hi, ikbf_lo, 2097152L, nullptr, nullptr, 0);

    // ---- indexer scores (MFMA bf16x3) + topk ----
    score3_k<<<dim3(T_/64, T_/64), 256, 0, stream>>>(iqbf_hi, iqbf_lo, ikbf_hi, ikbf_lo, wtok, score);
    topk_k<<<T_, 512, 0, stream>>>(score, topk);

    // ---- q_key assembly ----
    CAST(qbuf, qbf, nullptr, 3145728L, nullptr, nullptr, 0);       // into iq slot
    tcast_k<<<dim3(16, 4, 16), 256, 0, stream>>>(wkv_b, wkT);      // into ik slot
    qpe_k<<<T_*H_/2, 64, 0, stream>>>(qbuf, qkey, cosb, sinb);
    gemm_bt_mfma_k<<<dim3(KVLR_/128, T_/128, H_), 256, 0, stream>>>(
        qbf, wkT, qkey, 192L, 65536L, 576L, H_*QKD_, ID_, H_*CKV_, KVLR_, ID_, 0);

    // ---- attention -> out_latent ----
    attn2_k<<<T_, 256, 0, stream>>>(qkey, kvkey, topk, olat);

    // ---- out_v = out_latent @ w_v^T (bf16 batched, 64-tile) ----
    CAST(olat, olat_bf, nullptr, 8388608L, nullptr, nullptr, 0);
    CAST(wkv_b, wkvb_bf, nullptr, 2097152L, nullptr, nullptr, 0);
    gemm_bt64_k<<<dim3(VD_/64, T_/64, H_), 256, 0, stream>>>(
        olat_bf, wkvb_bf + (long)NOPE_*KVLR_, outv,
        512L, (long)(NOPE_+VD_)*KVLR_, (long)VD_,
        H_*KVLR_, KVLR_, H_*VD_, VD_, KVLR_, 0);

    // ---- out = outv @ wo.T (bf16) ----
    CAST(outv, outv_bf, nullptr, 2097152L, nullptr, nullptr, 0);
    CAST(wo,   wo_bf,   nullptr, 4194304L, nullptr, nullptr, 0);
    gemm_bt64_k<<<dim3(DIM_/64, T_/64, 1), 256, 0, stream>>>(
        outv_bf, wo_bf, out, 0,0,0, H_*VD_, H_*VD_, DIM_, DIM_, H_*VD_, 0);

    #undef CAST
    (void)in_sizes; (void)n_in; (void)out_size; (void)ws_size;
}

// Round 5
// 623.548 us; speedup vs baseline: 6.4834x; 1.3597x over previous
//
#include <hip/hip_runtime.h>
#include <hip/hip_bf16.h>
#include <math.h>

// Problem constants
#define T_     1024
#define DIM_   2048
#define H_     16
#define QLR_   1024
#define KVLR_  512
#define NOPE_  128
#define ROPE_  64
#define VD_    128
#define QKD_   192   // NOPE+ROPE
#define IH_    16
#define ID_    128
#define TOPK_  256
#define CKV_   576   // KVLR + ROPE

#define SCALE_W    0.022097086912079608f   // IH^-0.5 * ID^-0.5
#define SCALE_LOG  0.07216878364870323f    // QKD^-0.5

typedef short bfrag __attribute__((ext_vector_type(8)));   // 8 bf16 = 4 VGPRs
typedef float ffrag __attribute__((ext_vector_type(4)));   // 4 fp32 acc

__device__ __forceinline__ unsigned short f2bf(float f) {
    union { __hip_bfloat16 h; unsigned short u; } c; c.h = __float2bfloat16(f); return c.u;
}
__device__ __forceinline__ float bf2f(unsigned short u) {
    union { unsigned short u; __hip_bfloat16 h; } c; c.u = u; return __bfloat162float(c.h);
}

// ---------------------------------------------------------------------------
// fp32 -> bf16 cast, optional hi/lo split and per-row/col scaling.
// ---------------------------------------------------------------------------
__global__ __launch_bounds__(256) void cast_hl_k(
    const float* __restrict__ in, unsigned short* __restrict__ hi,
    unsigned short* __restrict__ lo, long n,
    const float* __restrict__ colw, const float* __restrict__ rowscale, int Kc)
{
    long base = ((long)blockIdx.x * 256 + threadIdx.x) * 4;
    if (base >= n) return;
    float4 v = *(const float4*)(in + base);
    float s[4] = {v.x, v.y, v.z, v.w};
    if (colw) {
        int col = (int)(base % Kc);
        float4 cw = *(const float4*)(colw + col);
        s[0] *= cw.x; s[1] *= cw.y; s[2] *= cw.z; s[3] *= cw.w;
    }
    if (rowscale) {
        float r = rowscale[base / Kc];
        s[0] *= r; s[1] *= r; s[2] *= r; s[3] *= r;
    }
    ushort4 h4;
    h4.x = f2bf(s[0]); h4.y = f2bf(s[1]); h4.z = f2bf(s[2]); h4.w = f2bf(s[3]);
    *(ushort4*)(hi + base) = h4;
    if (lo) {
        ushort4 l4;
        l4.x = f2bf(s[0] - bf2f(h4.x));
        l4.y = f2bf(s[1] - bf2f(h4.y));
        l4.z = f2bf(s[2] - bf2f(h4.z));
        l4.w = f2bf(s[3] - bf2f(h4.w));
        *(ushort4*)(lo + base) = l4;
    }
}

// ---------------------------------------------------------------------------
// Transpose-cast w_k: wkT[h][c][d] = bf16(wkv_b[(h*256+d)*512 + c]), d<128, c<512
// ---------------------------------------------------------------------------
__global__ __launch_bounds__(256) void tcast_k(const float* __restrict__ in,
                                               unsigned short* __restrict__ out)
{
    int h = blockIdx.z, c0 = blockIdx.x * 32, d0 = blockIdx.y * 32;
    __shared__ float t[32][33];
    int tx = threadIdx.x & 31, ty = threadIdx.x >> 5;
    #pragma unroll
    for (int i = 0; i < 4; ++i)
        t[ty + i * 8][tx] = in[(long)(h * 256 + d0 + ty + i * 8) * 512 + c0 + tx];
    __syncthreads();
    #pragma unroll
    for (int i = 0; i < 4; ++i)
        out[((long)h * 512 + c0 + ty + i * 8) * 128 + d0 + tx] = f2bf(t[tx][ty + i * 8]);
}

// ---------------------------------------------------------------------------
// MFMA bf16 NT GEMM, 128x128 tile (batched q_nope_proj).
// ---------------------------------------------------------------------------
__global__ __launch_bounds__(256) void gemm_bt_mfma_k(
    const unsigned short* __restrict__ A, const unsigned short* __restrict__ B,
    float* __restrict__ C, long sA, long sB, long sC,
    int lda, int ldb, int ldc, int N, int K)
{
    A += (long)blockIdx.z * sA;
    B += (long)blockIdx.z * sB;
    C += (long)blockIdx.z * sC;
    __shared__ unsigned short As[128 * 40];
    __shared__ unsigned short Bs[128 * 40];
    const int tid = threadIdx.x;
    const int bm = blockIdx.y * 128, bn = blockIdx.x * 128;
    const int wave = tid >> 6, lane = tid & 63;
    const int wm = (wave >> 1) * 64, wn = (wave & 1) * 64;
    const int lm = lane & 15, quad = lane >> 4;

    ffrag acc[4][4];
    #pragma unroll
    for (int mi = 0; mi < 4; ++mi)
        #pragma unroll
        for (int ni = 0; ni < 4; ++ni)
            #pragma unroll
            for (int r = 0; r < 4; ++r) acc[mi][ni][r] = 0.f;

    const int srow = tid >> 1, shalf = tid & 1;
    const long aoff = (long)(bm + srow) * lda + shalf * 16;
    int brow = bn + srow; if (brow > N - 1) brow = N - 1;
    const long boff = (long)brow * ldb + shalf * 16;
    unsigned short* la = As + srow * 40 + shalf * 16;
    unsigned short* lb = Bs + srow * 40 + shalf * 16;

    for (int k0 = 0; k0 < K; k0 += 32) {
        __syncthreads();
        uint4 va0 = *(const uint4*)(A + aoff + k0);
        uint4 va1 = *(const uint4*)(A + aoff + k0 + 8);
        uint4 vb0 = *(const uint4*)(B + boff + k0);
        uint4 vb1 = *(const uint4*)(B + boff + k0 + 8);
        *(uint4*)la = va0; *(uint4*)(la + 8) = va1;
        *(uint4*)lb = vb0; *(uint4*)(lb + 8) = vb1;
        __syncthreads();
        bfrag af[4], bf[4];
        #pragma unroll
        for (int mi = 0; mi < 4; ++mi)
            af[mi] = *(const bfrag*)(As + (wm + mi * 16 + lm) * 40 + quad * 8);
        #pragma unroll
        for (int ni = 0; ni < 4; ++ni)
            bf[ni] = *(const bfrag*)(Bs + (wn + ni * 16 + lm) * 40 + quad * 8);
        #pragma unroll
        for (int mi = 0; mi < 4; ++mi)
            #pragma unroll
            for (int ni = 0; ni < 4; ++ni)
                acc[mi][ni] = __builtin_amdgcn_mfma_f32_16x16x32_bf16(
                    af[mi], bf[ni], acc[mi][ni], 0, 0, 0);
    }

    #pragma unroll
    for (int mi = 0; mi < 4; ++mi)
        #pragma unroll
        for (int ni = 0; ni < 4; ++ni) {
            int n = bn + wn + ni * 16 + lm;
            if (n < N) {
                int mb = bm + wm + mi * 16 + quad * 4;
                #pragma unroll
                for (int r = 0; r < 4; ++r)
                    C[(long)(mb + r) * ldc + n] = acc[mi][ni][r];
            }
        }
}

// ---------------------------------------------------------------------------
// MFMA bf16 NT GEMM, 64x64 tile. obf=1 -> write bf16 C (C is ushort*).
// ---------------------------------------------------------------------------
__global__ __launch_bounds__(256) void gemm_bt64_k(
    const unsigned short* __restrict__ A, const unsigned short* __restrict__ B,
    void* __restrict__ Cv, long sA, long sB, long sC,
    int lda, int ldb, int ldc, int N, int K, int obf)
{
    A += (long)blockIdx.z * sA;
    B += (long)blockIdx.z * sB;
    __shared__ unsigned short As[64 * 40];
    __shared__ unsigned short Bs[64 * 40];
    const int tid = threadIdx.x;
    const int bm = blockIdx.y * 64, bn = blockIdx.x * 64;
    const int wave = tid >> 6, lane = tid & 63;
    const int wm = (wave >> 1) * 32, wn = (wave & 1) * 32;
    const int lm = lane & 15, quad = lane >> 4;

    ffrag acc[2][2];
    #pragma unroll
    for (int mi = 0; mi < 2; ++mi)
        #pragma unroll
        for (int ni = 0; ni < 2; ++ni)
            #pragma unroll
            for (int r = 0; r < 4; ++r) acc[mi][ni][r] = 0.f;

    const int srow = tid >> 2, schunk = tid & 3;
    const long aoff = (long)(bm + srow) * lda + schunk * 8;
    int brow = bn + srow; if (brow > N - 1) brow = N - 1;
    const long boff = (long)brow * ldb + schunk * 8;
    unsigned short* la = As + srow * 40 + schunk * 8;
    unsigned short* lb = Bs + srow * 40 + schunk * 8;

    for (int k0 = 0; k0 < K; k0 += 32) {
        __syncthreads();
        uint4 va = *(const uint4*)(A + aoff + k0);
        uint4 vb = *(const uint4*)(B + boff + k0);
        *(uint4*)la = va;
        *(uint4*)lb = vb;
        __syncthreads();
        bfrag af[2], bf[2];
        #pragma unroll
        for (int mi = 0; mi < 2; ++mi)
            af[mi] = *(const bfrag*)(As + (wm + mi * 16 + lm) * 40 + quad * 8);
        #pragma unroll
        for (int ni = 0; ni < 2; ++ni)
            bf[ni] = *(const bfrag*)(Bs + (wn + ni * 16 + lm) * 40 + quad * 8);
        #pragma unroll
        for (int mi = 0; mi < 2; ++mi)
            #pragma unroll
            for (int ni = 0; ni < 2; ++ni)
                acc[mi][ni] = __builtin_amdgcn_mfma_f32_16x16x32_bf16(
                    af[mi], bf[ni], acc[mi][ni], 0, 0, 0);
    }

    #pragma unroll
    for (int mi = 0; mi < 2; ++mi)
        #pragma unroll
        for (int ni = 0; ni < 2; ++ni) {
            int n = bn + wn + ni * 16 + lm;
            if (n < N) {
                int mb = bm + wm + mi * 16 + quad * 4;
                if (obf) {
                    unsigned short* C = (unsigned short*)Cv + (long)blockIdx.z * sC;
                    #pragma unroll
                    for (int r = 0; r < 4; ++r)
                        C[(long)(mb + r) * ldc + n] = f2bf(acc[mi][ni][r]);
                } else {
                    float* C = (float*)Cv + (long)blockIdx.z * sC;
                    #pragma unroll
                    for (int r = 0; r < 4; ++r)
                        C[(long)(mb + r) * ldc + n] = acc[mi][ni][r];
                }
            }
        }
}

// ---------------------------------------------------------------------------
// Fused bf16x3 NT GEMM, 64x64 tile: C = Ah.Bh^T + Ah.Bl^T + Al.Bh^T
// M,N %64==0, K %32==0. Single pass replaces 3 beta-accumulate dispatches.
// ---------------------------------------------------------------------------
__global__ __launch_bounds__(256) void gemm3_bt64_k(
    const unsigned short* __restrict__ Ah, const unsigned short* __restrict__ Al,
    const unsigned short* __restrict__ Bh, const unsigned short* __restrict__ Bl,
    float* __restrict__ C, int lda, int ldb, int ldc, int K)
{
    __shared__ unsigned short Ahs[64 * 40], Als[64 * 40], Bhs[64 * 40], Bls[64 * 40];
    const int tid = threadIdx.x;
    const int bm = blockIdx.y * 64, bn = blockIdx.x * 64;
    const int wave = tid >> 6, lane = tid & 63;
    const int wm = (wave >> 1) * 32, wn = (wave & 1) * 32;
    const int lm = lane & 15, quad = lane >> 4;

    ffrag acc[2][2];
    #pragma unroll
    for (int mi = 0; mi < 2; ++mi)
        #pragma unroll
        for (int ni = 0; ni < 2; ++ni)
            #pragma unroll
            for (int r = 0; r < 4; ++r) acc[mi][ni][r] = 0.f;

    const int srow = tid >> 2, schunk = tid & 3;
    const long aoff = (long)(bm + srow) * lda + schunk * 8;
    const long boff = (long)(bn + srow) * ldb + schunk * 8;
    const int loff = srow * 40 + schunk * 8;

    for (int k0 = 0; k0 < K; k0 += 32) {
        __syncthreads();
        uint4 vah = *(const uint4*)(Ah + aoff + k0);
        uint4 val = *(const uint4*)(Al + aoff + k0);
        uint4 vbh = *(const uint4*)(Bh + boff + k0);
        uint4 vbl = *(const uint4*)(Bl + boff + k0);
        *(uint4*)(Ahs + loff) = vah;
        *(uint4*)(Als + loff) = val;
        *(uint4*)(Bhs + loff) = vbh;
        *(uint4*)(Bls + loff) = vbl;
        __syncthreads();
        bfrag ah[2], al[2], bh[2], bl[2];
        #pragma unroll
        for (int mi = 0; mi < 2; ++mi) {
            ah[mi] = *(const bfrag*)(Ahs + (wm + mi * 16 + lm) * 40 + quad * 8);
            al[mi] = *(const bfrag*)(Als + (wm + mi * 16 + lm) * 40 + quad * 8);
        }
        #pragma unroll
        for (int ni = 0; ni < 2; ++ni) {
            bh[ni] = *(const bfrag*)(Bhs + (wn + ni * 16 + lm) * 40 + quad * 8);
            bl[ni] = *(const bfrag*)(Bls + (wn + ni * 16 + lm) * 40 + quad * 8);
        }
        #pragma unroll
        for (int mi = 0; mi < 2; ++mi)
            #pragma unroll
            for (int ni = 0; ni < 2; ++ni) {
                acc[mi][ni] = __builtin_amdgcn_mfma_f32_16x16x32_bf16(ah[mi], bh[ni], acc[mi][ni], 0, 0, 0);
                acc[mi][ni] = __builtin_amdgcn_mfma_f32_16x16x32_bf16(ah[mi], bl[ni], acc[mi][ni], 0, 0, 0);
                acc[mi][ni] = __builtin_amdgcn_mfma_f32_16x16x32_bf16(al[mi], bh[ni], acc[mi][ni], 0, 0, 0);
            }
    }

    #pragma unroll
    for (int mi = 0; mi < 2; ++mi)
        #pragma unroll
        for (int ni = 0; ni < 2; ++ni) {
            int n = bn + wn + ni * 16 + lm;
            int mb = bm + wm + mi * 16 + quad * 4;
            #pragma unroll
            for (int r = 0; r < 4; ++r)
                C[(long)(mb + r) * ldc + n] = acc[mi][ni][r];
        }
}

// ---------------------------------------------------------------------------
// Fused wtok: wtok[t,h] = dot(x[t,:], wproj[h,:]) * SCALE_W  (fp32)
// ---------------------------------------------------------------------------
__global__ __launch_bounds__(256) void wtok_k(const float* __restrict__ x,
    const float* __restrict__ wproj, float* __restrict__ wtok)
{
    int t = blockIdx.x, tid = threadIdx.x;
    __shared__ float xs[DIM_];
    for (int c = tid; c < DIM_; c += 256) xs[c] = x[(long)t * DIM_ + c];
    __syncthreads();
    int wave = tid >> 6, lane = tid & 63;
    #pragma unroll
    for (int i = 0; i < 4; ++i) {
        int h = wave * 4 + i;
        float s = 0.f;
        for (int c = lane; c < DIM_; c += 64) s += xs[c] * wproj[(long)h * DIM_ + c];
        for (int off = 32; off; off >>= 1) s += __shfl_xor(s, off, 64);
        if (lane == 0) wtok[(long)t * IH_ + h] = s * SCALE_W;
    }
}

// ---------------------------------------------------------------------------
__global__ __launch_bounds__(256) void rstd_k(const float* __restrict__ qr, float* __restrict__ rstd)
{
    int t = blockIdx.x, tid = threadIdx.x;
    float s = 0.f;
    for (int c = tid; c < QLR_; c += 256) { float v = qr[(long)t * QLR_ + c]; s += v * v; }
    __shared__ float red[256];
    red[tid] = s; __syncthreads();
    for (int off = 128; off; off >>= 1) { if (tid < off) red[tid] += red[tid + off]; __syncthreads(); }
    if (tid == 0) rstd[t] = rsqrtf(red[0] / (float)QLR_ + 1e-6f);
}

// ---------------------------------------------------------------------------
__device__ __forceinline__ void rope_rotate_128(float* s, float* w2, int tid, int t,
    const float* __restrict__ cosb, const float* __restrict__ sinb)
{
    float n1 = 0.f, n2 = 0.f;
    if (tid < 32) {
        float x1 = s[tid], x2 = s[tid + 32];
        float c = cosb[t * 32 + tid], sn = sinb[t * 32 + tid];
        n1 = x1 * c - x2 * sn;
        n2 = x1 * sn + x2 * c;
    }
    __syncthreads();
    if (tid < 32) { s[tid] = n1; s[tid + 32] = n2; }
    __syncthreads();
    const int g = tid >> 6, p = tid & 63;
    w2[tid] = s[((1 - g) << 6) + p];
    __syncthreads();
    #pragma unroll
    for (int h = 1; h < 64; h <<= 1) {
        float a = w2[tid], b = w2[(g << 6) + (p ^ h)];
        __syncthreads();
        w2[tid] = (p & h) ? (b - a) : (a + b);
        __syncthreads();
    }
}

__global__ __launch_bounds__(128) void transform_iq_k(float* __restrict__ iq,
    const float* __restrict__ cosb, const float* __restrict__ sinb)
{
    int row = blockIdx.x;
    int t = row / IH_;
    int tid = threadIdx.x;
    __shared__ float s[128], w2[128];
    s[tid] = iq[(long)row * 128 + tid];
    __syncthreads();
    rope_rotate_128(s, w2, tid, t, cosb, sinb);
    iq[(long)row * 128 + tid] = w2[tid];
}

__global__ __launch_bounds__(128) void transform_ik_k(float* __restrict__ ik,
    const float* __restrict__ knw, const float* __restrict__ knb,
    const float* __restrict__ cosb, const float* __restrict__ sinb)
{
    int row = blockIdx.x;
    int t = row / IH_;
    int tid = threadIdx.x;
    __shared__ float s[128], w2[128], red[128];
    float v = ik[(long)row * 128 + tid];
    red[tid] = v; __syncthreads();
    for (int off = 64; off; off >>= 1) { if (tid < off) red[tid] += red[tid + off]; __syncthreads(); }
    float m = red[0] / 128.f; __syncthreads();
    float d = v - m;
    red[tid] = d * d; __syncthreads();
    for (int off = 64; off; off >>= 1) { if (tid < off) red[tid] += red[tid + off]; __syncthreads(); }
    float var = red[0] / 128.f;
    s[tid] = d * rsqrtf(var + 1e-5f) * knw[tid] + knb[tid];
    __syncthreads();
    rope_rotate_128(s, w2, tid, t, cosb, sinb);
    ik[(long)row * 128 + tid] = w2[tid];
}

__global__ __launch_bounds__(256) void transform_kv_k(const float* __restrict__ kva,
    float* __restrict__ kvkey, const float* __restrict__ kvnw,
    const float* __restrict__ cosb, const float* __restrict__ sinb)
{
    int t = blockIdx.x, tid = threadIdx.x;
    const float* a = kva + (long)t * CKV_;
    float* o = kvkey + (long)t * CKV_;
    float v0 = a[tid], v1 = a[tid + 256];
    __shared__ float red[256];
    __shared__ float rsh;
    red[tid] = v0 * v0 + v1 * v1; __syncthreads();
    for (int off = 128; off; off >>= 1) { if (tid < off) red[tid] += red[tid + off]; __syncthreads(); }
    if (tid == 0) rsh = rsqrtf(red[0] / (float)KVLR_ + 1e-6f);
    __syncthreads();
    float rs = rsh;
    o[tid]       = v0 * rs * kvnw[tid];
    o[tid + 256] = v1 * rs * kvnw[tid + 256];
    if (tid < 32) {
        float x1 = a[512 + tid], x2 = a[544 + tid];
        float c = cosb[t * 32 + tid], sn = sinb[t * 32 + tid];
        o[512 + tid] = x1 * c - x2 * sn;
        o[544 + tid] = x1 * sn + x2 * c;
    }
}

__global__ __launch_bounds__(64) void qpe_k(const float* __restrict__ q, float* __restrict__ qkey,
    const float* __restrict__ cosb, const float* __restrict__ sinb)
{
    int row = blockIdx.x * 2 + (threadIdx.x >> 5);
    int i = threadIdx.x & 31;
    int t = row / H_;
    const float* qp = q + (long)row * QKD_ + NOPE_;
    float x1 = qp[i], x2 = qp[i + 32];
    float c = cosb[t * 32 + i], sn = sinb[t * 32 + i];
    float* o = qkey + (long)row * CKV_ + 512;
    o[i]      = x1 * c - x2 * sn;
    o[i + 32] = x1 * sn + x2 * c;
}

// ---------------------------------------------------------------------------
// Indexer score (MFMA bf16x3)
// ---------------------------------------------------------------------------
__global__ __launch_bounds__(256) void score3_k(
    const unsigned short* __restrict__ iqh, const unsigned short* __restrict__ iql,
    const unsigned short* __restrict__ ikh, const unsigned short* __restrict__ ikl,
    const float* __restrict__ wtok, float* __restrict__ score)
{
    const int bt = blockIdx.y, bs = blockIdx.x;
    if (bs > bt) return;
    __shared__ unsigned short Ah[64 * 40], Al[64 * 40], Bh[64 * 40], Bl[64 * 40];
    __shared__ float wts[64][16];
    const int tid = threadIdx.x;
    const int wave = tid >> 6, lane = tid & 63;
    const int wm = (wave >> 1) * 32, wn = (wave & 1) * 32;
    const int lm = lane & 15, quad = lane >> 4;
    const int t0 = bt * 64, s0 = bs * 64;
    const int srow = tid >> 2, schunk = tid & 3;

    for (int e = tid; e < 1024; e += 256)
        wts[e >> 4][e & 15] = wtok[(long)(t0 + (e >> 4)) * IH_ + (e & 15)];

    float accf[2][2][4] = {};

    for (int h = 0; h < IH_; ++h) {
        ffrag acch[2][2];
        #pragma unroll
        for (int mi = 0; mi < 2; ++mi)
            #pragma unroll
            for (int ni = 0; ni < 2; ++ni)
                #pragma unroll
                for (int r = 0; r < 4; ++r) acch[mi][ni][r] = 0.f;

        #pragma unroll
        for (int k0 = 0; k0 < ID_; k0 += 32) {
            __syncthreads();
            const long ao = (long)(t0 + srow) * 2048 + h * 128 + k0 + schunk * 8;
            const long bo = (long)(s0 + srow) * 2048 + h * 128 + k0 + schunk * 8;
            *(uint4*)(Ah + srow * 40 + schunk * 8) = *(const uint4*)(iqh + ao);
            *(uint4*)(Al + srow * 40 + schunk * 8) = *(const uint4*)(iql + ao);
            *(uint4*)(Bh + srow * 40 + schunk * 8) = *(const uint4*)(ikh + bo);
            *(uint4*)(Bl + srow * 40 + schunk * 8) = *(const uint4*)(ikl + bo);
            __syncthreads();
            bfrag ah[2], alo[2], bh[2], blo[2];
            #pragma unroll
            for (int mi = 0; mi < 2; ++mi) {
                ah[mi]  = *(const bfrag*)(Ah + (wm + mi * 16 + lm) * 40 + quad * 8);
                alo[mi] = *(const bfrag*)(Al + (wm + mi * 16 + lm) * 40 + quad * 8);
            }
            #pragma unroll
            for (int ni = 0; ni < 2; ++ni) {
                bh[ni]  = *(const bfrag*)(Bh + (wn + ni * 16 + lm) * 40 + quad * 8);
                blo[ni] = *(const bfrag*)(Bl + (wn + ni * 16 + lm) * 40 + quad * 8);
            }
            #pragma unroll
            for (int mi = 0; mi < 2; ++mi)
                #pragma unroll
                for (int ni = 0; ni < 2; ++ni) {
                    acch[mi][ni] = __builtin_amdgcn_mfma_f32_16x16x32_bf16(ah[mi],  bh[ni],  acch[mi][ni], 0, 0, 0);
                    acch[mi][ni] = __builtin_amdgcn_mfma_f32_16x16x32_bf16(ah[mi],  blo[ni], acch[mi][ni], 0, 0, 0);
                    acch[mi][ni] = __builtin_amdgcn_mfma_f32_16x16x32_bf16(alo[mi], bh[ni],  acch[mi][ni], 0, 0, 0);
                }
        }
        #pragma unroll
        for (int mi = 0; mi < 2; ++mi) {
            float wr[4];
            #pragma unroll
            for (int r = 0; r < 4; ++r) wr[r] = wts[wm + mi * 16 + quad * 4 + r][h];
            #pragma unroll
            for (int ni = 0; ni < 2; ++ni)
                #pragma unroll
                for (int r = 0; r < 4; ++r)
                    accf[mi][ni][r] += fmaxf(acch[mi][ni][r], 0.f) * wr[r];
        }
    }
    #pragma unroll
    for (int mi = 0; mi < 2; ++mi)
        #pragma unroll
        for (int ni = 0; ni < 2; ++ni) {
            int s = s0 + wn + ni * 16 + lm;
            int tb = t0 + wm + mi * 16 + quad * 4;
            #pragma unroll
            for (int r = 0; r < 4; ++r)
                score[(long)(tb + r) * T_ + s] = accf[mi][ni][r];
        }
}

// ---------------------------------------------------------------------------
// Top-256 per row via bitonic sort (ties -> lower index, matches jax top_k)
// ---------------------------------------------------------------------------
__global__ __launch_bounds__(512) void topk_k(const float* __restrict__ score, int* __restrict__ topk)
{
    int t = blockIdx.x, tid = threadIdx.x;
    __shared__ float v[1024];
    __shared__ int ix[1024];
    for (int i = tid; i < 1024; i += 512) {
        v[i] = (i <= t) ? score[(long)t * T_ + i] : -INFINITY;
        ix[i] = i;
    }
    __syncthreads();
    for (int k = 2; k <= 1024; k <<= 1) {
        for (int j = k >> 1; j > 0; j >>= 1) {
            for (int i = tid; i < 1024; i += 512) {
                int l = i ^ j;
                if (l > i) {
                    bool up = ((i & k) == 0);
                    float vi = v[i], vl = v[l];
                    int xi = ix[i], xl = ix[l];
                    bool iBetter = (vi > vl) || (vi == vl && xi < xl);
                    bool doSwap = up ? !iBetter : iBetter;
                    if (doSwap) { v[i] = vl; v[l] = vi; ix[i] = xl; ix[l] = xi; }
                }
            }
            __syncthreads();
        }
    }
    if (tid < 256) topk[(long)t * TOPK_ + tid] = ix[tid];
}

// ---------------------------------------------------------------------------
// Attention v3 (MFMA bf16): one block per token, 4 waves.
// Phase A: logits[16h][256k] = Q(16x576) . K^T, fp32 softmax, P->bf16.
// Phase B: olat[16h][512c] = P(16x256) . V, V transpose-staged per 32-key step.
// kvb: kvkey in bf16 [1024][576]. qkey fp32 (cast in-kernel). olat written bf16.
// LDS map (ushort units): Qbf[16*592]@0, SelA[256*40]@9472, Lg(fp32)@19712,
// Pbf[16*264]@28160; VT[512*40]@0 (aliases Qbf+SelA+head of Lg, phase B only).
// ---------------------------------------------------------------------------
__global__ __launch_bounds__(256) void attn3_k(
    const float* __restrict__ qkey, const unsigned short* __restrict__ kvb,
    const int* __restrict__ topkp, unsigned short* __restrict__ olat)
{
    __shared__ unsigned short U[32384];
    __shared__ float red[16 * 17];
    __shared__ int kidx[256];
    unsigned short* Qbf  = U;                    // [16][592]
    unsigned short* SelA = U + 9472;             // [256][40]
    float*          Lg   = (float*)(U + 19712);  // [16][264]
    unsigned short* Pbf  = U + 28160;            // [16][264]
    unsigned short* VT   = U;                    // [512][40] (phase B)

    const int t = blockIdx.x, tid = threadIdx.x;
    const int wave = tid >> 6, lane = tid & 63;
    const int lm = lane & 15, quad = lane >> 4;

    kidx[tid] = topkp[(long)t * TOPK_ + tid];
    // stage + cast Q row: 9216 floats -> Qbf[16][592]
    const float4* q4 = (const float4*)(qkey + (long)t * (H_ * CKV_));
    #pragma unroll
    for (int rep = 0; rep < 9; ++rep) {
        int e4 = rep * 256 + tid;
        float4 v = q4[e4];
        int f = e4 * 4, h = f / CKV_, c = f - h * CKV_;
        ushort4 u4; u4.x = f2bf(v.x); u4.y = f2bf(v.y); u4.z = f2bf(v.z); u4.w = f2bf(v.w);
        *(ushort4*)(Qbf + h * 592 + c) = u4;
    }
    __syncthreads();

    // ---- Phase A ----
    ffrag acc[4];
    #pragma unroll
    for (int ni = 0; ni < 4; ++ni)
        #pragma unroll
        for (int r = 0; r < 4; ++r) acc[ni][r] = 0.f;

    for (int c0 = 0; c0 < CKV_; c0 += 32) {
        __syncthreads();
        #pragma unroll
        for (int rep = 0; rep < 4; ++rep) {
            int idx = rep * 256 + tid;
            int key = idx >> 2, u = idx & 3;
            uint4 v = *(const uint4*)(kvb + (long)kidx[key] * CKV_ + c0 + u * 8);
            *(uint4*)(SelA + key * 40 + u * 8) = v;
        }
        __syncthreads();
        bfrag af = *(const bfrag*)(Qbf + lm * 592 + c0 + quad * 8);
        #pragma unroll
        for (int ni = 0; ni < 4; ++ni) {
            bfrag bf = *(const bfrag*)(SelA + (wave * 64 + ni * 16 + lm) * 40 + quad * 8);
            acc[ni] = __builtin_amdgcn_mfma_f32_16x16x32_bf16(af, bf, acc[ni], 0, 0, 0);
        }
    }
    __syncthreads();
    // write logits: D col=lane&15 (key), row=quad*4+r (head)
    #pragma unroll
    for (int ni = 0; ni < 4; ++ni)
        #pragma unroll
        for (int r = 0; r < 4; ++r)
            Lg[(quad * 4 + r) * 264 + wave * 64 + ni * 16 + lm] = acc[ni][r];
    __syncthreads();

    // ---- softmax (h = tid>>4, 16 threads/h over 16-key chunks) ----
    {
        int h = tid >> 4, j = tid & 15;
        float m = -INFINITY;
        #pragma unroll
        for (int kk = 0; kk < 16; ++kk) {
            int key = j * 16 + kk;
            if (kidx[key] <= t) m = fmaxf(m, Lg[h * 264 + key]);
        }
        red[h * 17 + j] = m;
        __syncthreads();
        float mh = -INFINITY;
        #pragma unroll
        for (int jj = 0; jj < 16; ++jj) mh = fmaxf(mh, red[h * 17 + jj]);
        __syncthreads();
        float s = 0.f;
        float pv[16];
        #pragma unroll
        for (int kk = 0; kk < 16; ++kk) {
            int key = j * 16 + kk;
            float e = (kidx[key] <= t) ? expf(Lg[h * 264 + key] * SCALE_LOG - mh * SCALE_LOG) : 0.f;
            pv[kk] = e; s += e;
        }
        red[h * 17 + j] = s;
        __syncthreads();
        float sh = 0.f;
        #pragma unroll
        for (int jj = 0; jj < 16; ++jj) sh += red[h * 17 + jj];
        float inv = 1.f / sh;
        #pragma unroll
        for (int kk = 0; kk < 16; ++kk)
            Pbf[h * 264 + j * 16 + kk] = f2bf(pv[kk] * inv);
    }
    __syncthreads();

    // ---- Phase B ----
    ffrag acc2[8];
    #pragma unroll
    for (int ci = 0; ci < 8; ++ci)
        #pragma unroll
        for (int r = 0; r < 4; ++r) acc2[ci][r] = 0.f;

    for (int k0 = 0; k0 < TOPK_; k0 += 32) {
        __syncthreads();
        #pragma unroll
        for (int rep = 0; rep < 8; ++rep) {
            int idx = rep * 256 + tid;
            int kk = idx & 31, cu = idx >> 5;   // cu: 0..63 (8 c's each)
            uint4 v = *(const uint4*)(kvb + (long)kidx[k0 + kk] * CKV_ + cu * 8);
            const unsigned short* us = (const unsigned short*)&v;
            #pragma unroll
            for (int i = 0; i < 8; ++i)
                VT[(cu * 8 + i) * 40 + kk] = us[i];
        }
        __syncthreads();
        bfrag pa = *(const bfrag*)(Pbf + lm * 264 + k0 + quad * 8);
        #pragma unroll
        for (int ci = 0; ci < 8; ++ci) {
            bfrag bv = *(const bfrag*)(VT + (wave * 128 + ci * 16 + lm) * 40 + quad * 8);
            acc2[ci] = __builtin_amdgcn_mfma_f32_16x16x32_bf16(pa, bv, acc2[ci], 0, 0, 0);
        }
    }
    // store olat bf16: [t*16 + h][512], h = quad*4+r, c = wave*128 + ci*16 + lm
    #pragma unroll
    for (int ci = 0; ci < 8; ++ci)
        #pragma unroll
        for (int r = 0; r < 4; ++r)
            olat[((long)t * H_ + quad * 4 + r) * 512 + wave * 128 + ci * 16 + lm] = f2bf(acc2[ci][r]);
}

// ---------------------------------------------------------------------------
extern "C" void kernel_launch(void* const* d_in, const int* in_sizes, int n_in,
                              void* d_out, int out_size, void* d_ws, size_t ws_size,
                              hipStream_t stream)
{
    const float* x          = (const float*)d_in[0];
    const float* cosb       = (const float*)d_in[1];
    const float* sinb       = (const float*)d_in[2];
    const float* wq_a       = (const float*)d_in[3];
    const float* q_norm_w   = (const float*)d_in[4];
    const float* wq_b       = (const float*)d_in[5];
    const float* wkv_a      = (const float*)d_in[6];
    const float* kv_norm_w  = (const float*)d_in[7];
    const float* wkv_b      = (const float*)d_in[8];
    const float* wo         = (const float*)d_in[9];
    const float* iq_norm_w  = (const float*)d_in[10];
    const float* iwq_b      = (const float*)d_in[11];
    const float* iwk        = (const float*)d_in[12];
    const float* k_norm_w   = (const float*)d_in[13];
    const float* k_norm_b   = (const float*)d_in[14];
    const float* wproj      = (const float*)d_in[15];
    float* out = (float*)d_out;

    // fp32 workspace (float offsets)
    float* ws    = (float*)d_ws;
    float* qr    = ws;                      // 1,048,576 (dead after qr casts -> kvb)
    float* rstd  = ws + 1048576;
    float* wtok  = ws + 1049600;
    float* kvkey = ws + 1065984;            // 589,824
    int*   topk  = (int*)(ws + 1655808);    // 262,144 ints
    float* qkey  = ws + 1917952;            // 9,437,184
    float* outv  = ws + 11355136;           // 2,097,152 (slot)
    float* U0    = ws + 13452288;           // union region
    float* iq    = U0;                      // 2,097,152
    float* ik    = U0 + 2097152;            // 2,097,152
    float* kva   = U0 + 4194304;            // 589,824
    float* qbuf  = U0 + 4784128;            // 3,145,728
    float* score = U0 + 7929856;            // 1,048,576

    // bf16 sublayouts (ushort units)
    unsigned short* qkey_u = (unsigned short*)qkey;      // free until qpe/qnope
    unsigned short* wqa_hi  = qkey_u;
    unsigned short* wqa_lo  = qkey_u + 2097152;
    unsigned short* iwk_hi  = qkey_u + 4194304;
    unsigned short* iwk_lo  = qkey_u + 8388608;
    unsigned short* iwqb_hi = qkey_u + 12582912;
    unsigned short* iwqb_lo = qkey_u + 14680064;
    unsigned short* qriq_hi = qkey_u + 16777216;
    unsigned short* qriq_lo = qkey_u + 17825792;
    // mid-phase: score bf16 inputs (over dead early casts)
    unsigned short* iqbf_hi = qkey_u;
    unsigned short* iqbf_lo = qkey_u + 2097152;
    unsigned short* ikbf_hi = qkey_u + 4194304;
    unsigned short* ikbf_lo = qkey_u + 6291456;
    // late-phase (qkey dead after attn3):
    unsigned short* wkvb_bf = qkey_u + 8388608;
    unsigned short* wo_bf   = qkey_u + 12582912;
    // q slot early reuse:
    unsigned short* q_u     = (unsigned short*)qbuf;
    unsigned short* x_hi    = q_u;
    unsigned short* x_lo    = q_u + 2097152;
    unsigned short* wkva_hi = q_u + 4194304;
    // outv slot early reuse:
    unsigned short* outv_u  = (unsigned short*)outv;
    unsigned short* wqb_hi  = outv_u;                    // dead after q GEMM
    unsigned short* qrq_hi  = outv_u + 3145728;
    unsigned short* outv_bf = outv_u;                    // outv GEMM writes bf16 here
    // iq / ik slots (dead after score3 input casts):
    unsigned short* qbf     = (unsigned short*)iq;
    unsigned short* wkT     = (unsigned short*)ik;
    // qr slot (dead after qriq/qrq casts): kvkey bf16
    unsigned short* kvb     = (unsigned short*)qr;
    // olat bf16 at U0 (iq+ik slots, dead after qnope GEMM)
    unsigned short* olat_bf = (unsigned short*)U0;       // 8,388,608 us

    #define CAST(src, hi, lo, n, cw, rs, K) \
        cast_hl_k<<<(n)/1024, 256, 0, stream>>>((src), (hi), (lo), (n), (cw), (rs), (K))

    // ---- casts (early) ----
    CAST(x,     x_hi,   x_lo,   2097152L, nullptr, nullptr, 0);
    CAST(wq_a,  wqa_hi, wqa_lo, 2097152L, nullptr, nullptr, 0);
    CAST(iwk,   iwk_hi, iwk_lo, 4194304L, nullptr, nullptr, 0);
    CAST(iwq_b, iwqb_hi,iwqb_lo,2097152L, nullptr, nullptr, 0);
    CAST(wkv_a, wkva_hi,nullptr,1179648L, nullptr, nullptr, 0);
    CAST(wq_b,  wqb_hi, nullptr,3145728L, nullptr, nullptr, 0);

    // ---- qr = x @ wq_a.T (fused bf16x3) ----
    gemm3_bt64_k<<<dim3(QLR_/64, T_/64), 256, 0, stream>>>(
        x_hi, x_lo, wqa_hi, wqa_lo, qr, DIM_, DIM_, QLR_, DIM_);

    rstd_k<<<T_, 256, 0, stream>>>(qr, rstd);
    CAST(qr, qriq_hi, qriq_lo, 1048576L, iq_norm_w, rstd, QLR_);
    CAST(qr, qrq_hi,  nullptr, 1048576L, q_norm_w,  rstd, QLR_);

    // ---- iq / ik (fused bf16x3) ----
    gemm3_bt64_k<<<dim3(IH_*ID_/64, T_/64), 256, 0, stream>>>(
        qriq_hi, qriq_lo, iwqb_hi, iwqb_lo, iq, QLR_, QLR_, IH_*ID_, QLR_);
    gemm3_bt64_k<<<dim3(IH_*ID_/64, T_/64), 256, 0, stream>>>(
        x_hi, x_lo, iwk_hi, iwk_lo, ik, DIM_, DIM_, IH_*ID_, DIM_);

    // ---- kva = x @ wkv_a.T (bf16, N=576 guarded) ----
    gemm_bt64_k<<<dim3((CKV_+63)/64, T_/64, 1), 256, 0, stream>>>(
        x_hi, wkva_hi, kva, 0,0,0, DIM_, DIM_, CKV_, CKV_, DIM_, 0);

    // ---- q = rmsnorm(qr,q_norm) @ wq_b.T (bf16) ----
    gemm_bt64_k<<<dim3(H_*QKD_/64, T_/64, 1), 256, 0, stream>>>(
        qrq_hi, wqb_hi, qbuf, 0,0,0, QLR_, QLR_, H_*QKD_, H_*QKD_, QLR_, 0);

    // ---- wtok ----
    wtok_k<<<T_, 256, 0, stream>>>(x, wproj, wtok);

    // ---- per-row transforms ----
    transform_iq_k<<<T_*IH_, 128, 0, stream>>>(iq, cosb, sinb);
    transform_ik_k<<<T_*IH_, 128, 0, stream>>>(ik, k_norm_w, k_norm_b, cosb, sinb);
    transform_kv_k<<<T_, 256, 0, stream>>>(kva, kvkey, kv_norm_w, cosb, sinb);

    // ---- kvkey -> bf16 (into dead qr slot) ----
    CAST(kvkey, kvb, nullptr, 589824L, nullptr, nullptr, 0);

    // ---- score bf16 hi/lo casts + score + topk ----
    CAST(iq, iqbf_hi, iqbf_lo, 2097152L, nullptr, nullptr, 0);
    CAST(ik, ikbf_hi, ikbf_lo, 2097152L, nullptr, nullptr, 0);
    score3_k<<<dim3(T_/64, T_/64), 256, 0, stream>>>(iqbf_hi, iqbf_lo, ikbf_hi, ikbf_lo, wtok, score);
    topk_k<<<T_, 512, 0, stream>>>(score, topk);

    // ---- q_key assembly (qkey fp32) ----
    CAST(qbuf, qbf, nullptr, 3145728L, nullptr, nullptr, 0);
    tcast_k<<<dim3(16, 4, 16), 256, 0, stream>>>(wkv_b, wkT);
    qpe_k<<<T_*H_/2, 64, 0, stream>>>(qbuf, qkey, cosb, sinb);
    gemm_bt_mfma_k<<<dim3(KVLR_/128, T_/128, H_), 256, 0, stream>>>(
        qbf, wkT, qkey, 192L, 65536L, 576L, H_*QKD_, ID_, H_*CKV_, KVLR_, ID_);

    // ---- attention (MFMA) -> olat bf16 @ U0 ----
    attn3_k<<<T_, 256, 0, stream>>>(qkey, kvb, topk, olat_bf);

    // ---- out_v = out_latent @ w_v^T (bf16 batched, bf16 out) ----
    CAST(wkv_b, wkvb_bf, nullptr, 2097152L, nullptr, nullptr, 0);   // qkey region now dead
    gemm_bt64_k<<<dim3(VD_/64, T_/64, H_), 256, 0, stream>>>(
        olat_bf, wkvb_bf + (long)NOPE_*KVLR_, outv_bf,
        512L, (long)(NOPE_+VD_)*KVLR_, (long)VD_,
        H_*KVLR_, KVLR_, H_*VD_, VD_, KVLR_, 1);

    // ---- out = outv @ wo.T (bf16) ----
    CAST(wo, wo_bf, nullptr, 4194304L, nullptr, nullptr, 0);
    gemm_bt64_k<<<dim3(DIM_/64, T_/64, 1), 256, 0, stream>>>(
        outv_bf, wo_bf, out, 0,0,0, H_*VD_, H_*VD_, DIM_, DIM_, H_*VD_, 0);

    #undef CAST
    (void)in_sizes; (void)n_in; (void)out_size; (void)ws_size;
}